// Round 15
// baseline (2340.304 us; speedup 1.0000x reference)
//
#include <hip/hip_runtime.h>
#include <cstdint>
#include <cstddef>

typedef unsigned short u16;
typedef unsigned int   u32;
typedef float f32x4 __attribute__((ext_vector_type(4)));
typedef short s16x8 __attribute__((ext_vector_type(8)));
typedef u32   u32x4 __attribute__((ext_vector_type(4)));

#define DEV static __device__ __forceinline__
// wait + scheduling fence (rule #18: hipcc hoists reg-only MFMA past inline-asm waits)
#define WAIT0SB() do{ asm volatile("s_waitcnt vmcnt(0)" ::: "memory"); __builtin_amdgcn_sched_barrier(0); }while(0)

// ---------------- problem sizes ----------------
// B=32 P=256 L=32 V=30000 DE=DP=256 NH=8 DH=32 DFF=1024 NL=4, NSEQ=8192

// ---------------- ws layout (bytes) ----------------
static constexpr size_t OFF_EMBB = 0;            // bf16 [30000][256]
static constexpr size_t OFF_WP1  = 15360000;     // bf16 frag-packed [K1;R1] (1MB, 64 chunks x 16KB)
static constexpr size_t OFF_WP2  = 16408576;     // bf16 frag-packed [K2;R2] (1MB)
static constexpr size_t OFF_BQKV = 17457152;     // bf16 [4][768][256]
static constexpr size_t OFF_WOT  = 19030016;     // bf16 [4][256][256]
static constexpr size_t OFF_W1ET = 19554304;     // bf16 [4][1024][256]
static constexpr size_t OFF_W2ET = 21651456;     // bf16 [4][256][1024]
static constexpr size_t OFF_CIT  = 23748608;     // f32  [32][256][256] (C_i^T per mat)
static constexpr size_t OFF_HALL = 32137216;     // f32  [8192][256]
static constexpr size_t OFF_X    = 40525824;     // f32  [8192][256]
static constexpr size_t OFF_XB   = 48914432;     // bf16 [8192][256]
static constexpr size_t OFF_Y    = 53108736;     // f32  [8192][256]
static constexpr size_t OFF_QKV  = 61497344;     // bf16 [8192][768]
static constexpr size_t OFF_AO   = 74080256;     // bf16 [8192][256]
static constexpr size_t OFF_F    = 78274560;     // bf16 [8192][1024]
static constexpr size_t OFF_RV   = 95051776;     // f32  [32][256]
static constexpr size_t OFF_HB   = 95084544;     // bf16 [32][256]
static constexpr size_t OFF_LOG  = 95100928;     // f32  [32][30000]
// LSTM h double-buffers + barrier table live in the dead X..RV region during k_lstm3
static constexpr size_t OFF_H1A  = OFF_X;                 // bf16 [8192][256] = 4MB
static constexpr size_t OFF_H1B  = OFF_X + 4194304;
static constexpr size_t OFF_H2A  = OFF_X + 8388608;
static constexpr size_t OFF_H2B  = OFF_X + 12582912;
static constexpr size_t OFF_BARC = OFF_X + 16777216;      // u32 arr[256]

// ---------------- helpers ----------------
DEV u16 f2bf(float f){ u32 u = __builtin_bit_cast(u32, f); u += 0x7fffu + ((u>>16)&1u); return (u16)(u>>16); }
DEV float bf2f(u16 v){ return __builtin_bit_cast(float, (u32)v<<16); }
DEV float sigm(float x){ return 1.f/(1.f+__expf(-x)); }
DEV float tanh_f(float x){ float e=__expf(-2.f*fabsf(x)); float t=(1.f-e)/(1.f+e); return x<0.f? -t:t; }
DEV f32x4 splat4(float x){ f32x4 v={x,x,x,x}; return v; }
DEV f32x4 mfma16(s16x8 a, s16x8 b, f32x4 c){ return __builtin_amdgcn_mfma_f32_16x16x32_bf16(a,b,c,0,0,0); }

// XOR swizzles on 16B chunks within a row (row widths 256/128/32 bf16 elems)
DEV int swz256(int row, int col){ int ch=col>>3; return row*256 + (((ch ^ (row&7))&31)<<3) + (col&7); }
DEV int swz128(int row, int col){ int ch=col>>3; return row*128 + (((ch ^ (row&7))&15)<<3) + (col&7); }
DEV int swz32 (int row, int col){ int ch=col>>3; return row*32  + (((ch ^ (row&3))&3)<<3)  + (col&7); }

// ---------------- scope-explicit memory helpers (gfx940+ sc0/sc1 cpol; LLC scope ONLY —
// the XCD-L2-scope path is unvalidated and hung r14; never gate liveness on it) ----------------
DEV void st32_s(u32* p, u32 v){
  asm volatile("global_store_dword %0, %1, off sc0 sc1" :: "v"(p), "v"(v) : "memory");
}
DEV u32x4 ld128_s(const u32* p){
  u32x4 r;
  asm volatile("global_load_dwordx4 %0, %1, off sc0 sc1\n\ts_waitcnt vmcnt(0)" : "=v"(r) : "v"(p) : "memory");
  return r;
}
DEV void st128_s(u16* p, s16x8 v){
  asm volatile("global_store_dwordx4 %0, %1, off sc0 sc1" :: "v"(p), "v"(v) : "memory");
}
// issue 16 x 16B h-operand loads (two per-lane row addresses, 8 x 64B-offset each), NO wait.
DEV void ld16_iss(const u16* pa, const u16* pb, s16x8 r[16]){
  asm volatile(
    "global_load_dwordx4 %0, %16, off sc0 sc1\n\t"
    "global_load_dwordx4 %1, %16, off offset:64 sc0 sc1\n\t"
    "global_load_dwordx4 %2, %16, off offset:128 sc0 sc1\n\t"
    "global_load_dwordx4 %3, %16, off offset:192 sc0 sc1\n\t"
    "global_load_dwordx4 %4, %16, off offset:256 sc0 sc1\n\t"
    "global_load_dwordx4 %5, %16, off offset:320 sc0 sc1\n\t"
    "global_load_dwordx4 %6, %16, off offset:384 sc0 sc1\n\t"
    "global_load_dwordx4 %7, %16, off offset:448 sc0 sc1\n\t"
    "global_load_dwordx4 %8, %17, off sc0 sc1\n\t"
    "global_load_dwordx4 %9, %17, off offset:64 sc0 sc1\n\t"
    "global_load_dwordx4 %10, %17, off offset:128 sc0 sc1\n\t"
    "global_load_dwordx4 %11, %17, off offset:192 sc0 sc1\n\t"
    "global_load_dwordx4 %12, %17, off offset:256 sc0 sc1\n\t"
    "global_load_dwordx4 %13, %17, off offset:320 sc0 sc1\n\t"
    "global_load_dwordx4 %14, %17, off offset:384 sc0 sc1\n\t"
    "global_load_dwordx4 %15, %17, off offset:448 sc0 sc1"
    : "=&v"(r[0]),"=&v"(r[1]),"=&v"(r[2]),"=&v"(r[3]),
      "=&v"(r[4]),"=&v"(r[5]),"=&v"(r[6]),"=&v"(r[7]),
      "=&v"(r[8]),"=&v"(r[9]),"=&v"(r[10]),"=&v"(r[11]),
      "=&v"(r[12]),"=&v"(r[13]),"=&v"(r[14]),"=&v"(r[15])
    : "v"(pa), "v"(pb) : "memory");
}

// ---------------- fence-free distributed grid barrier (LLC arrivals) ----------------
// Ordering: each wave drains its own vmcnt at the entry __syncthreads (compiler semantics)
// BEFORE any arrival is published; consumers observe arrivals only via LLC.
DEV void gbar(u32* arr, u32 gen){
  __syncthreads();
  if (threadIdx.x==0){
    asm volatile("s_waitcnt vmcnt(0)" ::: "memory");
    st32_s(arr + blockIdx.x, gen);
  }
  if (threadIdx.x < 64){
    bool done = false;
    do {
      u32x4 q = ld128_s(arr + threadIdx.x*4);
      done = __all(q.x>=gen && q.y>=gen && q.z>=gen && q.w>=gen);
      if (!done) __builtin_amdgcn_s_sleep(2);
    } while(!done);
  }
  __syncthreads();
}

// ---------------- prep: transposes (f32 -> bf16/f32, dst[n][k] = src[k][n]) ----------------
struct TJob { const float* src; u32 dstOff; int K; int N; int stride; int f32out; };
struct PrepArgs { TJob j[60]; };

__global__ void k_prep(PrepArgs pa, char* __restrict__ ws){
  TJob jb = pa.j[blockIdx.y];
  int tilesK = jb.K >> 5, tilesN = jb.N >> 5;
  int ti = blockIdx.x;
  if (ti >= tilesK*tilesN) return;
  int tk = ti % tilesK, tn = ti / tilesK;
  __shared__ float tile[32][33];
  int r = threadIdx.x >> 5, c = threadIdx.x & 31;
  #pragma unroll
  for (int rr=0; rr<32; rr+=8)
    tile[rr+r][c] = jb.src[(size_t)(tk*32+rr+r)*jb.N + tn*32 + c];
  __syncthreads();
  if (jb.f32out){
    float* dst = (float*)(ws + jb.dstOff);
    #pragma unroll
    for (int rr=0; rr<32; rr+=8)
      dst[(size_t)(tn*32+rr+r)*jb.stride + tk*32 + c] = tile[c][rr+r];
  } else {
    u16* dst = (u16*)(ws + jb.dstOff);
    #pragma unroll
    for (int rr=0; rr<32; rr+=8)
      dst[(size_t)(tn*32+rr+r)*jb.stride + tk*32 + c] = f2bf(tile[c][rr+r]);
  }
}

__global__ void k_embcvt(const float* __restrict__ src, u16* __restrict__ dst, int n4){
  int i = blockIdx.x*blockDim.x + threadIdx.x;
  if (i >= n4) return;
  float4 v = ((const float4*)src)[i];
  uint2 pk;
  pk.x = f2bf(v.x) | ((u32)f2bf(v.y)<<16);
  pk.y = f2bf(v.z) | ((u32)f2bf(v.w)<<16);
  ((uint2*)dst)[i] = pk;
}

// ---------------- fragment packer (64 chunks x [hs:16][lane:64] x 16B per layer) ----------------
__global__ void k_packfrag(const float* __restrict__ srcA, const float* __restrict__ srcB,
                           u16* __restrict__ dst)
{
  int gid = blockIdx.x*256 + threadIdx.x;   // 65536 total
  int lane = gid & 63;
  int hs   = (gid>>6) & 15;
  int c    = gid >> 10;                     // 0..63
  int kc = c>>2, g = c&3;
  int l4 = lane>>4, l15 = lane&15;
  int col = g*256 + hs*16 + l15;
  int k0  = kc*32 + l4*8;
  u16 out[8];
  #pragma unroll
  for (int j=0;j<8;++j){
    int k = k0 + j;
    float v = (k < 256) ? srcA[(size_t)k*1024 + col] : srcB[(size_t)(k-256)*1024 + col];
    out[j] = f2bf(v);
  }
  *(s16x8*)(dst + (size_t)gid*8) = *(const s16x8*)out;
}

// ---------------- persistent fused 2-layer LSTM (LDS weights, 1 barrier/step, LLC h-path,
// LDS-staged coalesced h-stores: the r13 per-thread 2B scattered LLC stores caused ~5x
// write amplification (WRITE_SIZE 1.39GB vs 268MB ideal) + long vmcnt drains) ----------------
__global__ __launch_bounds__(1024,4) void k_lstm3(
    const int* __restrict__ tokens, const u16* __restrict__ EMBB,
    const u16* __restrict__ WP1, const u16* __restrict__ WP2,
    const float* __restrict__ b1, const float* __restrict__ b2,
    u16* __restrict__ H1A, u16* __restrict__ H1B,
    u16* __restrict__ H2A, u16* __restrict__ H2B,
    u32* __restrict__ bar, float* __restrict__ Hall)
{
  __shared__ u16 W1s[64*512];    // 64KB
  __shared__ u16 W2s[64*512];    // 64KB
  __shared__ u16 Hst[512*16];    // 16KB: this WG's h slice [512 local seq][16 dims], staging
  const int tid=threadIdx.x, lane=tid&63, v=tid>>6, l15=lane&15, l4=lane>>4;
  const int bid=blockIdx.x, sg=bid&15, hs=bid>>4;
  const int seq0w = sg*512 + v*32;
  u32* arr = bar;

  #pragma unroll
  for (int i=0;i<4;++i){
    int c = v*4+i;
    const u16* s1 = WP1 + ((size_t)(c*16+hs))*512 + lane*8;
    const u16* s2 = WP2 + ((size_t)(c*16+hs))*512 + lane*8;
    __builtin_amdgcn_global_load_lds((const __attribute__((address_space(1))) void*)s1,
        (__attribute__((address_space(3))) void*)(W1s + c*512), 16, 0, 0);
    __builtin_amdgcn_global_load_lds((const __attribute__((address_space(1))) void*)s2,
        (__attribute__((address_space(3))) void*)(W2s + c*512), 16, 0, 0);
  }
  float bl1[4], bl2[4];
  #pragma unroll
  for (int g=0;g<4;++g){ bl1[g]=b1[g*256 + hs*16 + l15]; bl2[g]=b2[g*256 + hs*16 + l15]; }
  asm volatile("s_waitcnt vmcnt(0)" ::: "memory");
  __syncthreads();

  float c1[8], c2[8];
  #pragma unroll
  for (int i=0;i<8;++i){ c1[i]=0.f; c2[i]=0.f; }
  const int row0 = seq0w + l15, row1 = seq0w + 16 + l15;
  const int cq = tid>>1, chf = tid&1;                 // cooperative-store role
  u32 gen = 0;

  #pragma unroll 1
  for (int t=0;t<32;++t){
    const u16* H1r = (t&1)? H1B : H1A;  u16* H1w = (t&1)? H1A : H1B;
    const u16* H2r = (t&1)? H2B : H2A;  u16* H2w = (t&1)? H2A : H2B;
    const int tok0 = tokens[row0*32 + t], tok1 = tokens[row1*32 + t];
    f32x4 acc[2][4];
    s16x8 r[16];
    // ---- layer 1: z1 = [e_t | h1(t-1)] @ [K1;R1] + b1 ----
    ld16_iss(H1r + (size_t)row0*256 + l4*8, H1r + (size_t)row1*256 + l4*8, r);
    #pragma unroll
    for (int g=0;g<4;++g){ acc[0][g]=splat4(bl1[g]); acc[1][g]=splat4(bl1[g]); }
    #pragma unroll
    for (int kc=0;kc<8;++kc){
      s16x8 fa0 = *(const s16x8*)(EMBB + (size_t)tok0*256 + kc*32 + l4*8);
      s16x8 fa1 = *(const s16x8*)(EMBB + (size_t)tok1*256 + kc*32 + l4*8);
      #pragma unroll
      for (int g=0;g<4;++g){
        s16x8 wf = *(const s16x8*)&W1s[(kc*4+g)*512 + lane*8];
        acc[0][g]=mfma16(fa0,wf,acc[0][g]);
        acc[1][g]=mfma16(fa1,wf,acc[1][g]);
      }
    }
    WAIT0SB();                                  // h1(t-1) operands landed (hidden under EMBB MFMAs)
    #pragma unroll
    for (int k2=0;k2<8;++k2){
      #pragma unroll
      for (int g=0;g<4;++g){
        s16x8 wf = *(const s16x8*)&W1s[((8+k2)*4+g)*512 + lane*8];
        acc[0][g]=mfma16(r[k2],wf,acc[0][g]);
        acc[1][g]=mfma16(r[8+k2],wf,acc[1][g]);
      }
    }
    #pragma unroll
    for (int m=0;m<2;++m)
      #pragma unroll
      for (int rr=0;rr<4;++rr){
        int idx=m*4+rr;
        float zi=acc[m][0][rr], zf=acc[m][1][rr], zg=acc[m][2][rr], zo=acc[m][3][rr];
        float cc=sigm(zf)*c1[idx]+sigm(zi)*tanh_f(zg);
        c1[idx]=cc;
        Hst[(v*32 + m*16 + l4*4 + rr)*16 + l15] = f2bf(sigm(zo)*tanh_f(cc));
      }
    __syncthreads();                            // h1 slice staged in LDS
    st128_s(H1w + (size_t)(sg*512 + cq)*256 + hs*16 + chf*8, *(const s16x8*)&Hst[cq*16 + chf*8]);
    ++gen; gbar(arr, gen);   // A(t): h1(t) visible; h2(t-1) (stored pre-barrier) visible
    // ---- layer 2: z2 = [h1(t) | h2(t-1)] @ [K2;R2] + b2 ----
    #pragma unroll
    for (int g=0;g<4;++g){ acc[0][g]=splat4(bl2[g]); acc[1][g]=splat4(bl2[g]); }
    ld16_iss(H1w + (size_t)row0*256 + l4*8, H1w + (size_t)row1*256 + l4*8, r);
    WAIT0SB();
    #pragma unroll
    for (int k2=0;k2<8;++k2){
      #pragma unroll
      for (int g=0;g<4;++g){
        s16x8 wf = *(const s16x8*)&W2s[(k2*4+g)*512 + lane*8];
        acc[0][g]=mfma16(r[k2],wf,acc[0][g]);
        acc[1][g]=mfma16(r[8+k2],wf,acc[1][g]);
      }
    }
    ld16_iss(H2r + (size_t)row0*256 + l4*8, H2r + (size_t)row1*256 + l4*8, r);
    WAIT0SB();
    #pragma unroll
    for (int k2=0;k2<8;++k2){
      #pragma unroll
      for (int g=0;g<4;++g){
        s16x8 wf = *(const s16x8*)&W2s[((8+k2)*4+g)*512 + lane*8];
        acc[0][g]=mfma16(r[k2],wf,acc[0][g]);
        acc[1][g]=mfma16(r[8+k2],wf,acc[1][g]);
      }
    }
    __syncthreads();                            // cooperative h1-store readers done with Hst
    #pragma unroll
    for (int m=0;m<2;++m)
      #pragma unroll
      for (int rr=0;rr<4;++rr){
        int idx=m*4+rr;
        float zi=acc[m][0][rr], zf=acc[m][1][rr], zg=acc[m][2][rr], zo=acc[m][3][rr];
        float cc=sigm(zf)*c2[idx]+sigm(zi)*tanh_f(zg);
        c2[idx]=cc;
        float h=sigm(zo)*tanh_f(cc);
        Hst[(v*32 + m*16 + l4*4 + rr)*16 + l15] = f2bf(h);
        if (t==31) Hall[(size_t)(seq0w + m*16 + l4*4 + rr)*256 + hs*16 + l15] = h;
      }
    __syncthreads();                            // h2 slice staged in LDS
    st128_s(H2w + (size_t)(sg*512 + cq)*256 + hs*16 + chf*8, *(const s16x8*)&Hst[cq*16 + chf*8]);
    // no barrier here: h2(t) publishes at A(t+1) (stores drain at its entry __syncthreads)
  }
}

// ---------------- generic bf16 GEMM: C[M][N] = A[M][K] @ Bt[N][K]^T ----------------
template<int BM, int EPI>
__global__ __launch_bounds__(512,2) void k_gemm(
    const u16* __restrict__ A, const u16* __restrict__ Bt, void* __restrict__ Cv,
    const float* __restrict__ bias, const float* __restrict__ Res,
    int M, int N, int K, int ldC)
{
  __shared__ u16 Asl[BM*256];
  const int tid=threadIdx.x, lane=tid&63, w=tid>>6, l15=lane&15, l4=lane>>4;
  const int mb=blockIdx.x, nb=blockIdx.y;
  constexpr int MT = BM/16;
  const int col0 = nb*256 + w*32;
  float bz0=0.f, bz1=0.f;
  if (EPI==1 || EPI==3 || EPI==5){ bz0 = bias[col0 + l15]; bz1 = bias[col0 + 16 + l15]; }
  f32x4 acc[MT][2];
  #pragma unroll
  for (int mt=0;mt<MT;++mt){ acc[mt][0]=splat4(bz0); acc[mt][1]=splat4(bz1); }
  for (int kb=0; kb<K; kb+=256){
    __syncthreads();
    if (tid < BM*8){
      int row=tid>>3, part=tid&7;
      int arow = mb*BM+row; if (arow > M-1) arow = M-1;
      const u16* src = A + (size_t)arow*K + kb + part*32;
      #pragma unroll
      for (int i=0;i<4;++i)
        *(s16x8*)&Asl[swz256(row, part*32+i*8)] = *(const s16x8*)(src+i*8);
    }
    __syncthreads();
    #pragma unroll
    for (int kc=0; kc<8; ++kc){
      s16x8 fa[MT];
      #pragma unroll
      for (int mt=0;mt<MT;++mt)
        fa[mt] = *(const s16x8*)&Asl[swz256(mt*16+l15, kc*32 + l4*8)];
      #pragma unroll
      for (int n=0;n<2;++n){
        int brow = col0 + n*16 + l15; if (brow > N-1) brow = N-1;
        const s16x8 fb = *(const s16x8*)(Bt + (size_t)brow*K + kb + kc*32 + l4*8);
        #pragma unroll
        for (int mt=0;mt<MT;++mt) acc[mt][n] = mfma16(fa[mt], fb, acc[mt][n]);
      }
    }
  }
  #pragma unroll
  for (int mt=0;mt<MT;++mt){
    #pragma unroll
    for (int n=0;n<2;++n){
      #pragma unroll
      for (int r=0;r<4;++r){
        int row = mb*BM + mt*16 + l4*4 + r;
        int col = col0 + n*16 + l15;
        if (col < N && row < M){
          float v = acc[mt][n][r];
          if (EPI==0){ ((u16*)Cv)[(size_t)row*ldC + col] = f2bf(v); }
          else if (EPI==1){ ((u16*)Cv)[(size_t)row*ldC + col] = f2bf(fmaxf(v,0.f)); }
          else if (EPI==2 || EPI==3){ ((float*)Cv)[(size_t)row*ldC + col] = v + Res[(size_t)row*ldC + col]; }
          else if (EPI==5){ ((u16*)Cv)[(size_t)row*ldC + col] = f2bf(v); }
          else { ((float*)Cv)[(size_t)row*ldC + col] = v; }
        }
      }
    }
  }
}

// ---------------- attention, one WG per (b,h) ----------------
__global__ __launch_bounds__(256) void k_attn(const u16* __restrict__ QKV, u16* __restrict__ AO,
                                              const int* __restrict__ pc)
{
  __shared__ u16 Qs[256*32];
  __shared__ u16 Ks[256*32];
  __shared__ u16 Vt[32*256];
  __shared__ u16 Ab[4][64*128];
  const int bh=blockIdx.x, b=bh>>3, h=bh&7;
  const int tid=threadIdx.x, lane=tid&63, w=tid>>6, l15=lane&15, l4=lane>>4;
  const int pcm1 = pc[b]-1;
  {
    int row = tid;
    const u16* base = QKV + (size_t)(b*256+row)*768 + h*32;
    #pragma unroll
    for (int i=0;i<4;++i){
      *(s16x8*)&Qs[swz32(row, i*8)] = *(const s16x8*)(base + i*8);
      *(s16x8*)&Ks[swz32(row, i*8)] = *(const s16x8*)(base + 256 + i*8);
    }
    #pragma unroll
    for (int i=0;i<4;++i){
      s16x8 v = *(const s16x8*)(base + 512 + i*8);
      #pragma unroll
      for (int j=0;j<8;++j){
        int d = i*8+j;
        Vt[d*256 + ((((row>>3) ^ (d&7))&31)<<3) + (row&7)] = (u16)v[j];
      }
    }
  }
  __syncthreads();
  const float scale = 0.17677669529663689f;
  const int q0w = w*64;
  float rmax[4][4], rinv[4][4];
  #pragma unroll 1
  for (int m=0;m<4;++m){
    f32x4 sacc[16];
    #pragma unroll
    for (int nt=0;nt<16;++nt) sacc[nt]=splat4(0.f);
    s16x8 fa = *(const s16x8*)&Qs[swz32(q0w+m*16+l15, l4*8)];
    #pragma unroll
    for (int nt=0;nt<16;++nt){
      s16x8 fb = *(const s16x8*)&Ks[swz32(nt*16+l15, l4*8)];
      sacc[nt] = mfma16(fa, fb, sacc[nt]);
    }
    #pragma unroll
    for (int r=0;r<4;++r){
      int q = q0w + m*16 + l4*4 + r;
      bool vq = q < pcm1;
      float sv[16]; float mx = -3e38f;
      #pragma unroll
      for (int nt=0;nt<16;++nt){
        int k = nt*16 + l15;
        float s = (vq && k < pcm1) ? sacc[nt][r]*scale : -1e9f;
        if (k == 255) s = -1e30f;
        sv[nt] = s; mx = fmaxf(mx, s);
      }
      #pragma unroll
      for (int msk=1;msk<16;msk<<=1) mx = fmaxf(mx, __shfl_xor(mx, msk, 64));
      float sum = 0.f;
      #pragma unroll
      for (int nt=0;nt<16;++nt) sum += __expf(sv[nt]-mx);
      #pragma unroll
      for (int msk=1;msk<16;msk<<=1) sum += __shfl_xor(sum, msk, 64);
      rmax[m][r]=mx; rinv[m][r]=1.f/sum;
    }
  }
  f32x4 oacc[4][2];
  #pragma unroll
  for (int m=0;m<4;++m){ oacc[m][0]=splat4(0.f); oacc[m][1]=splat4(0.f); }
  #pragma unroll 1
  for (int kg=0; kg<2; ++kg){
    #pragma unroll 1
    for (int m=0;m<4;++m){
      s16x8 fa = *(const s16x8*)&Qs[swz32(q0w+m*16+l15, l4*8)];
      #pragma unroll
      for (int nt2=0;nt2<8;++nt2){
        int nt = kg*8 + nt2;
        s16x8 fb = *(const s16x8*)&Ks[swz32(nt*16+l15, l4*8)];
        f32x4 sa = mfma16(fa, fb, splat4(0.f));
        #pragma unroll
        for (int r=0;r<4;++r){
          int q = q0w + m*16 + l4*4 + r;
          int k = nt*16 + l15;
          float s = (q < pcm1 && k < pcm1) ? sa[r]*scale : -1e9f;
          if (k == 255) s = -1e30f;
          float p = __expf(s - rmax[m][r]) * rinv[m][r];
          Ab[w][swz128(m*16 + l4*4 + r, nt2*16 + l15)] = f2bf(p);
        }
      }
    }
    #pragma unroll 1
    for (int m=0;m<4;++m){
      #pragma unroll
      for (int kc=0;kc<4;++kc){
        s16x8 fa2 = *(const s16x8*)&Ab[w][swz128(m*16+l15, kc*32 + l4*8)];
        #pragma unroll
        for (int n=0;n<2;++n){
          int d = n*16 + l15;
          int kch = kg*16 + kc*4 + l4;
          s16x8 fb = *(const s16x8*)&Vt[d*256 + (((kch ^ (d&7))&31)<<3)];
          oacc[m][n] = mfma16(fa2, fb, oacc[m][n]);
        }
      }
    }
  }
  #pragma unroll
  for (int m=0;m<4;++m){
    #pragma unroll
    for (int n=0;n<2;++n){
      #pragma unroll
      for (int r=0;r<4;++r){
        int q = q0w + m*16 + l4*4 + r;
        AO[(size_t)(b*256+q)*256 + h*32 + n*16 + l15] = f2bf(oacc[m][n][r]);
      }
    }
  }
}

// ---------------- LayerNorm (wave per row) ----------------
__global__ void k_ln(const float* __restrict__ Y, const float* __restrict__ g, const float* __restrict__ bb,
                     float* __restrict__ X, u16* __restrict__ Xb)
{
  int w = threadIdx.x >> 6, lane = threadIdx.x & 63;
  int row = blockIdx.x*4 + w;
  float4 v = ((const float4*)(Y + (size_t)row*256))[lane];
  float s = v.x+v.y+v.z+v.w;
  #pragma unroll
  for (int m=1;m<64;m<<=1) s += __shfl_xor(s, m, 64);
  float mean = s * (1.f/256.f);
  float dx=v.x-mean, dy=v.y-mean, dz=v.z-mean, dw=v.w-mean;
  float q = dx*dx+dy*dy+dz*dz+dw*dw;
  #pragma unroll
  for (int m=1;m<64;m<<=1) q += __shfl_xor(q, m, 64);
  float rstd = rsqrtf(q*(1.f/256.f) + 1e-5f);
  int c = lane*4;
  float o0=dx*rstd*g[c]+bb[c], o1=dy*rstd*g[c+1]+bb[c+1], o2=dz*rstd*g[c+2]+bb[c+2], o3=dw*rstd*g[c+3]+bb[c+3];
  float4 o; o.x=o0; o.y=o1; o.z=o2; o.w=o3;
  ((float4*)(X + (size_t)row*256))[lane] = o;
  uint2 pk; pk.x = f2bf(o0) | ((u32)f2bf(o1)<<16); pk.y = f2bf(o2) | ((u32)f2bf(o3)<<16);
  ((uint2*)(Xb + (size_t)row*256))[lane] = pk;
}

// ---------------- build masked encoder input ----------------
__global__ void k_buildZ(const float* __restrict__ Hall, const int* __restrict__ pc,
                         float* __restrict__ X, u16* __restrict__ Xb)
{
  int gid = blockIdx.x*256 + threadIdx.x;   // float4 id, 524288 total
  int row = gid >> 6;
  int b = row >> 8, p = row & 255;
  float4 v; v.x=v.y=v.z=v.w=0.f;
  if (p < pc[b]-1) v = ((const float4*)Hall)[gid];
  ((float4*)X)[gid] = v;
  uint2 pk; pk.x = f2bf(v.x) | ((u32)f2bf(v.y)<<16); pk.y = f2bf(v.z) | ((u32)f2bf(v.w)<<16);
  ((uint2*)Xb)[gid] = pk;
}

// ---------------- R vector: R = relu(C_i[tgt] @ R0) @ W_r ----------------
__global__ void k_rprep(const float* __restrict__ Hall, const int* __restrict__ pc, const int* __restrict__ tgt,
                        const float* __restrict__ CIT, const float* __restrict__ Wr, float* __restrict__ RV)
{
  int b = blockIdx.x, t = threadIdx.x;
  __shared__ float r0[256], ys[256];
  r0[t] = Hall[(size_t)(b*256 + pc[b]-1)*256 + t];
  __syncthreads();
  const float* Cb = CIT + (size_t)tgt[b]*65536;
  float a = 0.f;
  for (int j=0;j<256;++j) a += Cb[j*256 + t] * r0[j];
  ys[t] = fmaxf(a, 0.f);
  __syncthreads();
  float a2 = 0.f;
  for (int i=0;i<256;++i) a2 += Wr[i*256 + t] * ys[i];
  RV[b*256 + t] = a2;
}

// ---------------- pooling ----------------
__global__ void k_pool(const float* __restrict__ X, const float* __restrict__ RV,
                       const float* __restrict__ Wg, u16* __restrict__ HB)
{
  int b = blockIdx.x, t = threadIdx.x;
  __shared__ float R[256], al[256], red[256], zp[256];
  R[t] = RV[b*256+t];
  __syncthreads();
  float sc = -3e38f;
  if (t < 255){
    const float* z = X + (size_t)(b*256+t)*256;
    float a=0.f;
    for (int d=0;d<256;++d) a += z[d]*R[d];
    sc = a;
  }
  red[t] = sc;
  __syncthreads();
  for (int s=128;s>0;s>>=1){ if (t<s) red[t]=fmaxf(red[t],red[t+s]); __syncthreads(); }
  float M = red[0];
  __syncthreads();
  float e = (t<255) ? __expf(sc - M) : 0.f;
  red[t] = e;
  __syncthreads();
  for (int s=128;s>0;s>>=1){ if (t<s) red[t]+=red[t+s]; __syncthreads(); }
  float S = red[0];
  al[t] = e / S;
  __syncthreads();
  float acc = 0.f;
  for (int p=0;p<255;++p) acc += al[p] * X[(size_t)(b*256+p)*256 + t];
  zp[t] = acc;
  __syncthreads();
  float a2 = 0.f;
  for (int d=0;d<256;++d) a2 += zp[d] * Wg[d*256 + t];
  for (int d=0;d<256;++d) a2 += R[d]  * Wg[(256+d)*256 + t];
  HB[b*256+t] = f2bf(fmaxf(a2, 0.f));
}

// ---------------- final vocab softmax ----------------
__global__ void k_osm(const float* __restrict__ LOG, float* __restrict__ out)
{
  int b = blockIdx.x, t = threadIdx.x;  // 512 threads
  __shared__ float red[512];
  const float* Lp = LOG + (size_t)b*30000;
  float mx = -3e38f;
  for (int i=t;i<30000;i+=512) mx = fmaxf(mx, Lp[i]);
  red[t]=mx; __syncthreads();
  for (int s=256;s>0;s>>=1){ if (t<s) red[t]=fmaxf(red[t],red[t+s]); __syncthreads(); }
  float M = red[0]; __syncthreads();
  float sm = 0.f;
  for (int i=t;i<30000;i+=512) sm += __expf(Lp[i]-M);
  red[t]=sm; __syncthreads();
  for (int s=256;s>0;s>>=1){ if (t<s) red[t]+=red[t+s]; __syncthreads(); }
  float rinv = 1.f/red[0];
  float* O = out + (size_t)b*30000;
  for (int i=t;i<30000;i+=512) O[i] = __expf(Lp[i]-M) * rinv;
}

// ---------------- host ----------------
extern "C" void kernel_launch(void* const* d_in, const int* in_sizes, int n_in,
                              void* d_out, int out_size, void* d_ws, size_t ws_size,
                              hipStream_t stream)
{
  const int*   tokens = (const int*)  d_in[0];
  const int*   pc     = (const int*)  d_in[1];
  const int*   tgt    = (const int*)  d_in[2];
  const float* emb    = (const float*)d_in[3];
  const float* l1k    = (const float*)d_in[4];
  const float* l1r    = (const float*)d_in[5];
  const float* l1b    = (const float*)d_in[6];
  const float* l2k    = (const float*)d_in[7];
  const float* l2r    = (const float*)d_in[8];
  const float* l2b    = (const float*)d_in[9];
  const float* wq     = (const float*)d_in[10];
  const float* wk     = (const float*)d_in[11];
  const float* wv     = (const float*)d_in[12];
  const float* wo     = (const float*)d_in[13];
  const float* ln1g   = (const float*)d_in[14];
  const float* ln1b   = (const float*)d_in[15];
  const float* w1e    = (const float*)d_in[16];
  const float* b1e    = (const float*)d_in[17];
  const float* w2e    = (const float*)d_in[18];
  const float* b2e    = (const float*)d_in[19];
  const float* ln2g   = (const float*)d_in[20];
  const float* ln2b   = (const float*)d_in[21];
  const float* Wr     = (const float*)d_in[22];
  const float* Wg     = (const float*)d_in[23];
  const float* Ci     = (const float*)d_in[24];

  char* ws = (char*)d_ws;
  u16*   EMBB = (u16*)  (ws + OFF_EMBB);
  u16*   WP1  = (u16*)  (ws + OFF_WP1);
  u16*   WP2  = (u16*)  (ws + OFF_WP2);
  float* CIT  = (float*)(ws + OFF_CIT);
  float* HALL = (float*)(ws + OFF_HALL);
  float* X    = (float*)(ws + OFF_X);
  u16*   XB   = (u16*)  (ws + OFF_XB);
  float* Y    = (float*)(ws + OFF_Y);
  u16*   QKVb = (u16*)  (ws + OFF_QKV);
  u16*   AOb  = (u16*)  (ws + OFF_AO);
  u16*   Fb   = (u16*)  (ws + OFF_F);
  float* RV   = (float*)(ws + OFF_RV);
  u16*   HB   = (u16*)  (ws + OFF_HB);
  float* LOGp = (float*)(ws + OFF_LOG);
  u16*   H1A  = (u16*)  (ws + OFF_H1A);
  u16*   H1B  = (u16*)  (ws + OFF_H1B);
  u16*   H2A  = (u16*)  (ws + OFF_H2A);
  u16*   H2B  = (u16*)  (ws + OFF_H2B);
  u32*   BARC = (u32*)  (ws + OFF_BARC);

  PrepArgs pa;
  int ji = 0;
  auto addJ = [&](const float* s, size_t off, int K, int N, int stride, int f32o){
    pa.j[ji].src=s; pa.j[ji].dstOff=(u32)off; pa.j[ji].K=K; pa.j[ji].N=N; pa.j[ji].stride=stride; pa.j[ji].f32out=f32o; ++ji;
  };
  for (int l=0;l<4;++l) addJ(wq + l*65536,  OFF_BQKV + (size_t)(l*768      )*512, 256,256,256,0);
  for (int l=0;l<4;++l) addJ(wk + l*65536,  OFF_BQKV + (size_t)(l*768 + 256)*512, 256,256,256,0);
  for (int l=0;l<4;++l) addJ(wv + l*65536,  OFF_BQKV + (size_t)(l*768 + 512)*512, 256,256,256,0);
  for (int l=0;l<4;++l) addJ(wo + l*65536,  OFF_WOT  + (size_t)l*131072, 256,256,256,0);
  for (int l=0;l<4;++l) addJ(w1e + l*262144, OFF_W1ET + (size_t)l*524288, 256,1024,256,0);
  for (int l=0;l<4;++l) addJ(w2e + l*262144, OFF_W2ET + (size_t)l*524288, 1024,256,1024,0);
  for (int c=0;c<32;++c) addJ(Ci + (size_t)c*65536, OFF_CIT + (size_t)c*262144, 256,256,256,1);

  // zero h(-1) buffers + barrier arrival array
  hipMemsetAsync(ws + OFF_H1A, 0, 16777216 + 4096, stream);
  k_prep<<<dim3(256,56), dim3(256), 0, stream>>>(pa, ws);
  k_embcvt<<<dim3(7500), dim3(256), 0, stream>>>(emb, EMBB, 1920000);
  k_packfrag<<<dim3(256), dim3(256), 0, stream>>>(l1k, l1r, WP1);
  k_packfrag<<<dim3(256), dim3(256), 0, stream>>>(l2k, l2r, WP2);
  k_lstm3<<<dim3(256), dim3(1024), 0, stream>>>(tokens, EMBB, WP1, WP2, l1b, l2b,
                                                H1A, H1B, H2A, H2B, BARC, HALL);
  k_buildZ<<<dim3(2048), dim3(256), 0, stream>>>(HALL, pc, X, XB);
  k_rprep<<<dim3(32), dim3(256), 0, stream>>>(HALL, pc, tgt, CIT, Wr, RV);

  u16* BQKV = (u16*)(ws + OFF_BQKV);
  u16* WOT  = (u16*)(ws + OFF_WOT);
  u16* W1ET = (u16*)(ws + OFF_W1ET);
  u16* W2ET = (u16*)(ws + OFF_W2ET);
  for (int l=0;l<4;++l){
    k_gemm<64,0><<<dim3(128,3), dim3(512), 0, stream>>>(XB, BQKV + (size_t)l*768*256, QKVb, nullptr, nullptr, 8192, 768, 256, 768);
    k_attn<<<dim3(256), dim3(256), 0, stream>>>(QKVb, AOb, pc);
    k_gemm<64,2><<<dim3(128,1), dim3(512), 0, stream>>>(AOb, WOT + (size_t)l*65536, Y, nullptr, X, 8192, 256, 256, 256);
    k_ln<<<dim3(2048), dim3(256), 0, stream>>>(Y, ln1g + l*256, ln1b + l*256, X, XB);
    k_gemm<64,1><<<dim3(128,4), dim3(512), 0, stream>>>(XB, W1ET + (size_t)l*262144, Fb, b1e + l*1024, nullptr, 8192, 1024, 256, 1024);
    k_gemm<64,3><<<dim3(128,1), dim3(512), 0, stream>>>(Fb, W2ET + (size_t)l*262144, Y, b2e + l*256, X, 8192, 256, 1024, 256);
    k_ln<<<dim3(2048), dim3(256), 0, stream>>>(Y, ln2g + l*256, ln2b + l*256, X, XB);
  }

  k_pool<<<dim3(32), dim3(256), 0, stream>>>(X, RV, Wg, HB);
  k_gemm<32,4><<<dim3(1,118), dim3(512), 0, stream>>>(HB, EMBB, LOGp, nullptr, nullptr, 32, 30000, 256, 30000);
  k_osm<<<dim3(32), dim3(512), 0, stream>>>(LOGp, (float*)d_out);
}

// Round 16
// 2025.086 us; speedup vs baseline: 1.1557x; 1.1557x over previous
//
#include <hip/hip_runtime.h>
#include <cstdint>
#include <cstddef>

typedef unsigned short u16;
typedef unsigned int   u32;
typedef float f32x4 __attribute__((ext_vector_type(4)));
typedef short s16x8 __attribute__((ext_vector_type(8)));
typedef u32   u32x4 __attribute__((ext_vector_type(4)));

#define DEV static __device__ __forceinline__
// wait + scheduling fence (rule #18: hipcc hoists reg-only MFMA past inline-asm waits)
#define WAIT0SB() do{ asm volatile("s_waitcnt vmcnt(0)" ::: "memory"); __builtin_amdgcn_sched_barrier(0); }while(0)

// ---------------- problem sizes ----------------
// B=32 P=256 L=32 V=30000 DE=DP=256 NH=8 DH=32 DFF=1024 NL=4, NSEQ=8192

// ---------------- ws layout (bytes) ----------------
static constexpr size_t OFF_EMBB = 0;            // bf16 [30000][256]
static constexpr size_t OFF_WP1  = 15360000;     // bf16 frag-packed [K1;R1] (1MB, 64 chunks x 16KB)
static constexpr size_t OFF_WP2  = 16408576;     // bf16 frag-packed [K2;R2] (1MB)
static constexpr size_t OFF_BQKV = 17457152;     // bf16 [4][768][256]
static constexpr size_t OFF_WOT  = 19030016;     // bf16 [4][256][256]
static constexpr size_t OFF_W1ET = 19554304;     // bf16 [4][1024][256]
static constexpr size_t OFF_W2ET = 21651456;     // bf16 [4][256][1024]
static constexpr size_t OFF_CIT  = 23748608;     // f32  [32][256][256] (C_i^T per mat)
static constexpr size_t OFF_HALL = 32137216;     // f32  [8192][256]
static constexpr size_t OFF_X    = 40525824;     // f32  [8192][256]
static constexpr size_t OFF_XB   = 48914432;     // bf16 [8192][256]
static constexpr size_t OFF_QKV  = 61497344;     // bf16 [8192][768]
static constexpr size_t OFF_AO   = 74080256;     // bf16 [8192][256]
static constexpr size_t OFF_F    = 78274560;     // bf16 [8192][1024]
static constexpr size_t OFF_RV   = 95051776;     // f32  [32][256]
static constexpr size_t OFF_HB   = 95084544;     // bf16 [32][256]
static constexpr size_t OFF_LOG  = 95100928;     // f32  [32][30000]
// LSTM h double-buffers + barrier table live in the dead X..RV region during k_lstm3
static constexpr size_t OFF_H1A  = OFF_X;                 // bf16 [8192][256] = 4MB
static constexpr size_t OFF_H1B  = OFF_X + 4194304;
static constexpr size_t OFF_H2A  = OFF_X + 8388608;
static constexpr size_t OFF_H2B  = OFF_X + 12582912;
static constexpr size_t OFF_BARC = OFF_X + 16777216;      // u32 arr[256]

// ---------------- helpers ----------------
DEV u16 f2bf(float f){ u32 u = __builtin_bit_cast(u32, f); u += 0x7fffu + ((u>>16)&1u); return (u16)(u>>16); }
DEV float bf2f(u16 v){ return __builtin_bit_cast(float, (u32)v<<16); }
DEV float sigm(float x){ return 1.f/(1.f+__expf(-x)); }
DEV float tanh_f(float x){ float e=__expf(-2.f*fabsf(x)); float t=(1.f-e)/(1.f+e); return x<0.f? -t:t; }
DEV f32x4 splat4(float x){ f32x4 v={x,x,x,x}; return v; }
DEV f32x4 mfma16(s16x8 a, s16x8 b, f32x4 c){ return __builtin_amdgcn_mfma_f32_16x16x32_bf16(a,b,c,0,0,0); }

// XOR swizzles on 16B chunks within a row (row widths 256/128/32 bf16 elems)
DEV int swz256(int row, int col){ int ch=col>>3; return row*256 + (((ch ^ (row&7))&31)<<3) + (col&7); }
DEV int swz128(int row, int col){ int ch=col>>3; return row*128 + (((ch ^ (row&7))&15)<<3) + (col&7); }
DEV int swz32 (int row, int col){ int ch=col>>3; return row*32  + (((ch ^ (row&3))&3)<<3)  + (col&7); }

// ---------------- scope-explicit memory helpers (gfx940+ sc0/sc1 cpol; LLC scope ONLY —
// the XCD-L2-scope path is unvalidated and hung r14; never gate liveness on it) ----------------
DEV void st32_s(u32* p, u32 v){
  asm volatile("global_store_dword %0, %1, off sc0 sc1" :: "v"(p), "v"(v) : "memory");
}
DEV u32x4 ld128_s(const u32* p){
  u32x4 r;
  asm volatile("global_load_dwordx4 %0, %1, off sc0 sc1\n\ts_waitcnt vmcnt(0)" : "=v"(r) : "v"(p) : "memory");
  return r;
}
DEV void st16_s(u16* p, u16 v){
  asm volatile("global_store_short %0, %1, off sc0 sc1" :: "v"(p), "v"((u32)v) : "memory");
}
// issue 16 x 16B h-operand loads (two per-lane row addresses, 8 x 64B-offset each), NO wait.
DEV void ld16_iss(const u16* pa, const u16* pb, s16x8 r[16]){
  asm volatile(
    "global_load_dwordx4 %0, %16, off sc0 sc1\n\t"
    "global_load_dwordx4 %1, %16, off offset:64 sc0 sc1\n\t"
    "global_load_dwordx4 %2, %16, off offset:128 sc0 sc1\n\t"
    "global_load_dwordx4 %3, %16, off offset:192 sc0 sc1\n\t"
    "global_load_dwordx4 %4, %16, off offset:256 sc0 sc1\n\t"
    "global_load_dwordx4 %5, %16, off offset:320 sc0 sc1\n\t"
    "global_load_dwordx4 %6, %16, off offset:384 sc0 sc1\n\t"
    "global_load_dwordx4 %7, %16, off offset:448 sc0 sc1\n\t"
    "global_load_dwordx4 %8, %17, off sc0 sc1\n\t"
    "global_load_dwordx4 %9, %17, off offset:64 sc0 sc1\n\t"
    "global_load_dwordx4 %10, %17, off offset:128 sc0 sc1\n\t"
    "global_load_dwordx4 %11, %17, off offset:192 sc0 sc1\n\t"
    "global_load_dwordx4 %12, %17, off offset:256 sc0 sc1\n\t"
    "global_load_dwordx4 %13, %17, off offset:320 sc0 sc1\n\t"
    "global_load_dwordx4 %14, %17, off offset:384 sc0 sc1\n\t"
    "global_load_dwordx4 %15, %17, off offset:448 sc0 sc1"
    : "=&v"(r[0]),"=&v"(r[1]),"=&v"(r[2]),"=&v"(r[3]),
      "=&v"(r[4]),"=&v"(r[5]),"=&v"(r[6]),"=&v"(r[7]),
      "=&v"(r[8]),"=&v"(r[9]),"=&v"(r[10]),"=&v"(r[11]),
      "=&v"(r[12]),"=&v"(r[13]),"=&v"(r[14]),"=&v"(r[15])
    : "v"(pa), "v"(pb) : "memory");
}

// ---------------- fence-free distributed grid barrier (LLC arrivals) ----------------
DEV void gbar(u32* arr, u32 gen){
  __syncthreads();
  if (threadIdx.x==0){
    asm volatile("s_waitcnt vmcnt(0)" ::: "memory");
    st32_s(arr + blockIdx.x, gen);
  }
  if (threadIdx.x < 64){
    bool done = false;
    do {
      u32x4 q = ld128_s(arr + threadIdx.x*4);
      done = __all(q.x>=gen && q.y>=gen && q.z>=gen && q.w>=gen);
      if (!done) __builtin_amdgcn_s_sleep(2);
    } while(!done);
  }
  __syncthreads();
}

// ---------------- prep: transposes (f32 -> bf16/f32, dst[n][k] = src[k][n]) ----------------
struct TJob { const float* src; u32 dstOff; int K; int N; int stride; int f32out; };
struct PrepArgs { TJob j[60]; };

__global__ void k_prep(PrepArgs pa, char* __restrict__ ws){
  TJob jb = pa.j[blockIdx.y];
  int tilesK = jb.K >> 5, tilesN = jb.N >> 5;
  int ti = blockIdx.x;
  if (ti >= tilesK*tilesN) return;
  int tk = ti % tilesK, tn = ti / tilesK;
  __shared__ float tile[32][33];
  int r = threadIdx.x >> 5, c = threadIdx.x & 31;
  #pragma unroll
  for (int rr=0; rr<32; rr+=8)
    tile[rr+r][c] = jb.src[(size_t)(tk*32+rr+r)*jb.N + tn*32 + c];
  __syncthreads();
  if (jb.f32out){
    float* dst = (float*)(ws + jb.dstOff);
    #pragma unroll
    for (int rr=0; rr<32; rr+=8)
      dst[(size_t)(tn*32+rr+r)*jb.stride + tk*32 + c] = tile[c][rr+r];
  } else {
    u16* dst = (u16*)(ws + jb.dstOff);
    #pragma unroll
    for (int rr=0; rr<32; rr+=8)
      dst[(size_t)(tn*32+rr+r)*jb.stride + tk*32 + c] = f2bf(tile[c][rr+r]);
  }
}

__global__ void k_embcvt(const float* __restrict__ src, u16* __restrict__ dst, int n4){
  int i = blockIdx.x*blockDim.x + threadIdx.x;
  if (i >= n4) return;
  float4 v = ((const float4*)src)[i];
  uint2 pk;
  pk.x = f2bf(v.x) | ((u32)f2bf(v.y)<<16);
  pk.y = f2bf(v.z) | ((u32)f2bf(v.w)<<16);
  ((uint2*)dst)[i] = pk;
}

// ---------------- fragment packer (64 chunks x [hs:16][lane:64] x 16B per layer) ----------------
__global__ void k_packfrag(const float* __restrict__ srcA, const float* __restrict__ srcB,
                           u16* __restrict__ dst)
{
  int gid = blockIdx.x*256 + threadIdx.x;   // 65536 total
  int lane = gid & 63;
  int hs   = (gid>>6) & 15;
  int c    = gid >> 10;                     // 0..63
  int kc = c>>2, g = c&3;
  int l4 = lane>>4, l15 = lane&15;
  int col = g*256 + hs*16 + l15;
  int k0  = kc*32 + l4*8;
  u16 out[8];
  #pragma unroll
  for (int j=0;j<8;++j){
    int k = k0 + j;
    float v = (k < 256) ? srcA[(size_t)k*1024 + col] : srcB[(size_t)(k-256)*1024 + col];
    out[j] = f2bf(v);
  }
  *(s16x8*)(dst + (size_t)gid*8) = *(const s16x8*)out;
}

// ---------------- persistent fused 2-layer LSTM (r13 best-known config: LDS weights,
// one LLC grid barrier per step, scattered LLC h-stores; fast-path machinery removed) ----------------
__global__ __launch_bounds__(1024,4) void k_lstm3(
    const int* __restrict__ tokens, const u16* __restrict__ EMBB,
    const u16* __restrict__ WP1, const u16* __restrict__ WP2,
    const float* __restrict__ b1, const float* __restrict__ b2,
    u16* __restrict__ H1A, u16* __restrict__ H1B,
    u16* __restrict__ H2A, u16* __restrict__ H2B,
    u32* __restrict__ bar, float* __restrict__ Hall)
{
  __shared__ u16 W1s[64*512];   // 64KB
  __shared__ u16 W2s[64*512];   // 64KB
  const int tid=threadIdx.x, lane=tid&63, v=tid>>6, l15=lane&15, l4=lane>>4;
  const int bid=blockIdx.x, sg=bid&15, hs=bid>>4;
  const int seq0w = sg*512 + v*32;
  u32* arr = bar;

  #pragma unroll
  for (int i=0;i<4;++i){
    int c = v*4+i;
    const u16* s1 = WP1 + ((size_t)(c*16+hs))*512 + lane*8;
    const u16* s2 = WP2 + ((size_t)(c*16+hs))*512 + lane*8;
    __builtin_amdgcn_global_load_lds((const __attribute__((address_space(1))) void*)s1,
        (__attribute__((address_space(3))) void*)(W1s + c*512), 16, 0, 0);
    __builtin_amdgcn_global_load_lds((const __attribute__((address_space(1))) void*)s2,
        (__attribute__((address_space(3))) void*)(W2s + c*512), 16, 0, 0);
  }
  float bl1[4], bl2[4];
  #pragma unroll
  for (int g=0;g<4;++g){ bl1[g]=b1[g*256 + hs*16 + l15]; bl2[g]=b2[g*256 + hs*16 + l15]; }
  asm volatile("s_waitcnt vmcnt(0)" ::: "memory");
  __syncthreads();

  float c1[8], c2[8];
  #pragma unroll
  for (int i=0;i<8;++i){ c1[i]=0.f; c2[i]=0.f; }
  const int row0 = seq0w + l15, row1 = seq0w + 16 + l15;
  u32 gen = 0;

  #pragma unroll 1
  for (int t=0;t<32;++t){
    const u16* H1r = (t&1)? H1B : H1A;  u16* H1w = (t&1)? H1A : H1B;
    const u16* H2r = (t&1)? H2B : H2A;  u16* H2w = (t&1)? H2A : H2B;
    const int tok0 = tokens[row0*32 + t], tok1 = tokens[row1*32 + t];
    f32x4 acc[2][4];
    s16x8 r[16];
    // ---- layer 1: z1 = [e_t | h1(t-1)] @ [K1;R1] + b1 ----
    ld16_iss(H1r + (size_t)row0*256 + l4*8, H1r + (size_t)row1*256 + l4*8, r);
    #pragma unroll
    for (int g=0;g<4;++g){ acc[0][g]=splat4(bl1[g]); acc[1][g]=splat4(bl1[g]); }
    #pragma unroll
    for (int kc=0;kc<8;++kc){
      s16x8 fa0 = *(const s16x8*)(EMBB + (size_t)tok0*256 + kc*32 + l4*8);
      s16x8 fa1 = *(const s16x8*)(EMBB + (size_t)tok1*256 + kc*32 + l4*8);
      #pragma unroll
      for (int g=0;g<4;++g){
        s16x8 wf = *(const s16x8*)&W1s[(kc*4+g)*512 + lane*8];
        acc[0][g]=mfma16(fa0,wf,acc[0][g]);
        acc[1][g]=mfma16(fa1,wf,acc[1][g]);
      }
    }
    WAIT0SB();                                  // h1(t-1) operands landed (hidden under EMBB MFMAs)
    #pragma unroll
    for (int k2=0;k2<8;++k2){
      #pragma unroll
      for (int g=0;g<4;++g){
        s16x8 wf = *(const s16x8*)&W1s[((8+k2)*4+g)*512 + lane*8];
        acc[0][g]=mfma16(r[k2],wf,acc[0][g]);
        acc[1][g]=mfma16(r[8+k2],wf,acc[1][g]);
      }
    }
    #pragma unroll
    for (int m=0;m<2;++m)
      #pragma unroll
      for (int rr=0;rr<4;++rr){
        int idx=m*4+rr;
        float zi=acc[m][0][rr], zf=acc[m][1][rr], zg=acc[m][2][rr], zo=acc[m][3][rr];
        float cc=sigm(zf)*c1[idx]+sigm(zi)*tanh_f(zg);
        c1[idx]=cc;
        st16_s(H1w + (size_t)(seq0w + m*16 + l4*4 + rr)*256 + hs*16 + l15,
               f2bf(sigm(zo)*tanh_f(cc)));
      }
    ++gen; gbar(arr, gen);   // A(t): h1(t) visible; h2(t-1) (stored pre-barrier) visible
    // ---- layer 2: z2 = [h1(t) | h2(t-1)] @ [K2;R2] + b2 ----
    #pragma unroll
    for (int g=0;g<4;++g){ acc[0][g]=splat4(bl2[g]); acc[1][g]=splat4(bl2[g]); }
    ld16_iss(H1w + (size_t)row0*256 + l4*8, H1w + (size_t)row1*256 + l4*8, r);
    WAIT0SB();
    #pragma unroll
    for (int k2=0;k2<8;++k2){
      #pragma unroll
      for (int g=0;g<4;++g){
        s16x8 wf = *(const s16x8*)&W2s[(k2*4+g)*512 + lane*8];
        acc[0][g]=mfma16(r[k2],wf,acc[0][g]);
        acc[1][g]=mfma16(r[8+k2],wf,acc[1][g]);
      }
    }
    ld16_iss(H2r + (size_t)row0*256 + l4*8, H2r + (size_t)row1*256 + l4*8, r);
    WAIT0SB();
    #pragma unroll
    for (int k2=0;k2<8;++k2){
      #pragma unroll
      for (int g=0;g<4;++g){
        s16x8 wf = *(const s16x8*)&W2s[((8+k2)*4+g)*512 + lane*8];
        acc[0][g]=mfma16(r[k2],wf,acc[0][g]);
        acc[1][g]=mfma16(r[8+k2],wf,acc[1][g]);
      }
    }
    #pragma unroll
    for (int m=0;m<2;++m)
      #pragma unroll
      for (int rr=0;rr<4;++rr){
        int idx=m*4+rr;
        float zi=acc[m][0][rr], zf=acc[m][1][rr], zg=acc[m][2][rr], zo=acc[m][3][rr];
        float cc=sigm(zf)*c2[idx]+sigm(zi)*tanh_f(zg);
        c2[idx]=cc;
        float h=sigm(zo)*tanh_f(cc);
        st16_s(H2w + (size_t)(seq0w + m*16 + l4*4 + rr)*256 + hs*16 + l15, f2bf(h));
        if (t==31) Hall[(size_t)(seq0w + m*16 + l4*4 + rr)*256 + hs*16 + l15] = h;
      }
    // no barrier here: h2(t) publishes at A(t+1); kernel end syncs t=31
  }
}

// ---------------- generic bf16 GEMM: C[M][N] = A[M][K] @ Bt[N][K]^T ----------------
// EPI: 0 bf16; 1 +bias,relu,bf16; 4 f32 (guards); 5 +bias,bf16,M-guard;
//      6 +Res, LayerNorm -> X f32 + XB bf16 (N==256, full rows per block)
//      7 +bias +Res, LayerNorm -> X f32 + XB bf16
template<int BM, int EPI>
__global__ __launch_bounds__(512,2) void k_gemm(
    const u16* __restrict__ A, const u16* __restrict__ Bt, void* __restrict__ Cv,
    const float* __restrict__ bias, const float* __restrict__ Res,
    int M, int N, int K, int ldC,
    const float* __restrict__ lng, const float* __restrict__ lnb, u16* __restrict__ outB)
{
  __shared__ u16 Asl[BM*256];
  __shared__ float sS[512];
  __shared__ float sQ[512];
  const int tid=threadIdx.x, lane=tid&63, w=tid>>6, l15=lane&15, l4=lane>>4;
  const int mb=blockIdx.x, nb=blockIdx.y;
  constexpr int MT = BM/16;
  const int col0 = nb*256 + w*32;
  float bz0=0.f, bz1=0.f;
  if (EPI==1 || EPI==5 || EPI==7){ bz0 = bias[col0 + l15]; bz1 = bias[col0 + 16 + l15]; }
  f32x4 acc[MT][2];
  #pragma unroll
  for (int mt=0;mt<MT;++mt){ acc[mt][0]=splat4(bz0); acc[mt][1]=splat4(bz1); }
  for (int kb=0; kb<K; kb+=256){
    __syncthreads();
    if (tid < BM*8){
      int row=tid>>3, part=tid&7;
      int arow = mb*BM+row; if (arow > M-1) arow = M-1;
      const u16* src = A + (size_t)arow*K + kb + part*32;
      #pragma unroll
      for (int i=0;i<4;++i)
        *(s16x8*)&Asl[swz256(row, part*32+i*8)] = *(const s16x8*)(src+i*8);
    }
    __syncthreads();
    #pragma unroll
    for (int kc=0; kc<8; ++kc){
      s16x8 fa[MT];
      #pragma unroll
      for (int mt=0;mt<MT;++mt)
        fa[mt] = *(const s16x8*)&Asl[swz256(mt*16+l15, kc*32 + l4*8)];
      #pragma unroll
      for (int n=0;n<2;++n){
        int brow = col0 + n*16 + l15; if (brow > N-1) brow = N-1;
        const s16x8 fb = *(const s16x8*)(Bt + (size_t)brow*K + kb + kc*32 + l4*8);
        #pragma unroll
        for (int mt=0;mt<MT;++mt) acc[mt][n] = mfma16(fa[mt], fb, acc[mt][n]);
      }
    }
  }
  if constexpr (EPI==6 || EPI==7){
    // fused residual + LayerNorm; block holds full rows (N=256).
    float vv[MT][2][4];
    #pragma unroll
    for (int mt=0;mt<MT;++mt)
      #pragma unroll
      for (int n=0;n<2;++n)
        #pragma unroll
        for (int r=0;r<4;++r){
          int row = mb*BM + mt*16 + l4*4 + r;
          int col = col0 + n*16 + l15;
          vv[mt][n][r] = acc[mt][n][r] + Res[(size_t)row*256 + col];
        }
    #pragma unroll
    for (int mt=0;mt<MT;++mt)
      #pragma unroll
      for (int r=0;r<4;++r){
        float s = vv[mt][0][r] + vv[mt][1][r];
        float q = vv[mt][0][r]*vv[mt][0][r] + vv[mt][1][r]*vv[mt][1][r];
        #pragma unroll
        for (int msk=1;msk<16;msk<<=1){ s += __shfl_xor(s, msk, 64); q += __shfl_xor(q, msk, 64); }
        if (l15==0){ sS[w*64 + mt*16 + l4*4 + r] = s; sQ[w*64 + mt*16 + l4*4 + r] = q; }
      }
    __syncthreads();
    #pragma unroll
    for (int mt=0;mt<MT;++mt)
      #pragma unroll
      for (int r=0;r<4;++r){
        int lrow = mt*16 + l4*4 + r;
        float S=0.f, Q=0.f;
        #pragma unroll
        for (int w2=0;w2<8;++w2){ S += sS[w2*64 + lrow]; Q += sQ[w2*64 + lrow]; }
        float mean = S * (1.f/256.f);
        float var  = Q * (1.f/256.f) - mean*mean;
        float rstd = rsqrtf(var + 1e-5f);
        int row = mb*BM + lrow;
        #pragma unroll
        for (int n=0;n<2;++n){
          int col = col0 + n*16 + l15;
          float ov = (vv[mt][n][r]-mean)*rstd*lng[col] + lnb[col];
          ((float*)Cv)[(size_t)row*256 + col] = ov;
          outB[(size_t)row*256 + col] = f2bf(ov);
        }
      }
  } else {
    #pragma unroll
    for (int mt=0;mt<MT;++mt){
      #pragma unroll
      for (int n=0;n<2;++n){
        #pragma unroll
        for (int r=0;r<4;++r){
          int row = mb*BM + mt*16 + l4*4 + r;
          int col = col0 + n*16 + l15;
          if (col < N && row < M){
            float v = acc[mt][n][r];
            if (EPI==0){ ((u16*)Cv)[(size_t)row*ldC + col] = f2bf(v); }
            else if (EPI==1){ ((u16*)Cv)[(size_t)row*ldC + col] = f2bf(fmaxf(v,0.f)); }
            else if (EPI==5){ ((u16*)Cv)[(size_t)row*ldC + col] = f2bf(v); }
            else { ((float*)Cv)[(size_t)row*ldC + col] = v; }
          }
        }
      }
    }
  }
}

// ---------------- attention, one WG per (b,h) ----------------
__global__ __launch_bounds__(256) void k_attn(const u16* __restrict__ QKV, u16* __restrict__ AO,
                                              const int* __restrict__ pc)
{
  __shared__ u16 Qs[256*32];
  __shared__ u16 Ks[256*32];
  __shared__ u16 Vt[32*256];
  __shared__ u16 Ab[4][64*128];
  const int bh=blockIdx.x, b=bh>>3, h=bh&7;
  const int tid=threadIdx.x, lane=tid&63, w=tid>>6, l15=lane&15, l4=lane>>4;
  const int pcm1 = pc[b]-1;
  {
    int row = tid;
    const u16* base = QKV + (size_t)(b*256+row)*768 + h*32;
    #pragma unroll
    for (int i=0;i<4;++i){
      *(s16x8*)&Qs[swz32(row, i*8)] = *(const s16x8*)(base + i*8);
      *(s16x8*)&Ks[swz32(row, i*8)] = *(const s16x8*)(base + 256 + i*8);
    }
    #pragma unroll
    for (int i=0;i<4;++i){
      s16x8 v = *(const s16x8*)(base + 512 + i*8);
      #pragma unroll
      for (int j=0;j<8;++j){
        int d = i*8+j;
        Vt[d*256 + ((((row>>3) ^ (d&7))&31)<<3) + (row&7)] = (u16)v[j];
      }
    }
  }
  __syncthreads();
  const float scale = 0.17677669529663689f;
  const int q0w = w*64;
  float rmax[4][4], rinv[4][4];
  #pragma unroll 1
  for (int m=0;m<4;++m){
    f32x4 sacc[16];
    #pragma unroll
    for (int nt=0;nt<16;++nt) sacc[nt]=splat4(0.f);
    s16x8 fa = *(const s16x8*)&Qs[swz32(q0w+m*16+l15, l4*8)];
    #pragma unroll
    for (int nt=0;nt<16;++nt){
      s16x8 fb = *(const s16x8*)&Ks[swz32(nt*16+l15, l4*8)];
      sacc[nt] = mfma16(fa, fb, sacc[nt]);
    }
    #pragma unroll
    for (int r=0;r<4;++r){
      int q = q0w + m*16 + l4*4 + r;
      bool vq = q < pcm1;
      float sv[16]; float mx = -3e38f;
      #pragma unroll
      for (int nt=0;nt<16;++nt){
        int k = nt*16 + l15;
        float s = (vq && k < pcm1) ? sacc[nt][r]*scale : -1e9f;
        if (k == 255) s = -1e30f;
        sv[nt] = s; mx = fmaxf(mx, s);
      }
      #pragma unroll
      for (int msk=1;msk<16;msk<<=1) mx = fmaxf(mx, __shfl_xor(mx, msk, 64));
      float sum = 0.f;
      #pragma unroll
      for (int nt=0;nt<16;++nt) sum += __expf(sv[nt]-mx);
      #pragma unroll
      for (int msk=1;msk<16;msk<<=1) sum += __shfl_xor(sum, msk, 64);
      rmax[m][r]=mx; rinv[m][r]=1.f/sum;
    }
  }
  f32x4 oacc[4][2];
  #pragma unroll
  for (int m=0;m<4;++m){ oacc[m][0]=splat4(0.f); oacc[m][1]=splat4(0.f); }
  #pragma unroll 1
  for (int kg=0; kg<2; ++kg){
    #pragma unroll 1
    for (int m=0;m<4;++m){
      s16x8 fa = *(const s16x8*)&Qs[swz32(q0w+m*16+l15, l4*8)];
      #pragma unroll
      for (int nt2=0;nt2<8;++nt2){
        int nt = kg*8 + nt2;
        s16x8 fb = *(const s16x8*)&Ks[swz32(nt*16+l15, l4*8)];
        f32x4 sa = mfma16(fa, fb, splat4(0.f));
        #pragma unroll
        for (int r=0;r<4;++r){
          int q = q0w + m*16 + l4*4 + r;
          int k = nt*16 + l15;
          float s = (q < pcm1 && k < pcm1) ? sa[r]*scale : -1e9f;
          if (k == 255) s = -1e30f;
          float p = __expf(s - rmax[m][r]) * rinv[m][r];
          Ab[w][swz128(m*16 + l4*4 + r, nt2*16 + l15)] = f2bf(p);
        }
      }
    }
    #pragma unroll 1
    for (int m=0;m<4;++m){
      #pragma unroll
      for (int kc=0;kc<4;++kc){
        s16x8 fa2 = *(const s16x8*)&Ab[w][swz128(m*16+l15, kc*32 + l4*8)];
        #pragma unroll
        for (int n=0;n<2;++n){
          int d = n*16 + l15;
          int kch = kg*16 + kc*4 + l4;
          s16x8 fb = *(const s16x8*)&Vt[d*256 + (((kch ^ (d&7))&31)<<3)];
          oacc[m][n] = mfma16(fa2, fb, oacc[m][n]);
        }
      }
    }
  }
  #pragma unroll
  for (int m=0;m<4;++m){
    #pragma unroll
    for (int n=0;n<2;++n){
      #pragma unroll
      for (int r=0;r<4;++r){
        int q = q0w + m*16 + l4*4 + r;
        AO[(size_t)(b*256+q)*256 + h*32 + n*16 + l15] = f2bf(oacc[m][n][r]);
      }
    }
  }
}

// ---------------- build masked encoder input ----------------
__global__ void k_buildZ(const float* __restrict__ Hall, const int* __restrict__ pc,
                         float* __restrict__ X, u16* __restrict__ Xb)
{
  int gid = blockIdx.x*256 + threadIdx.x;   // float4 id, 524288 total
  int row = gid >> 6;
  int b = row >> 8, p = row & 255;
  float4 v; v.x=v.y=v.z=v.w=0.f;
  if (p < pc[b]-1) v = ((const float4*)Hall)[gid];
  ((float4*)X)[gid] = v;
  uint2 pk; pk.x = f2bf(v.x) | ((u32)f2bf(v.y)<<16); pk.y = f2bf(v.z) | ((u32)f2bf(v.w)<<16);
  ((uint2*)Xb)[gid] = pk;
}

// ---------------- R vector: R = relu(C_i[tgt] @ R0) @ W_r ----------------
__global__ void k_rprep(const float* __restrict__ Hall, const int* __restrict__ pc, const int* __restrict__ tgt,
                        const float* __restrict__ CIT, const float* __restrict__ Wr, float* __restrict__ RV)
{
  int b = blockIdx.x, t = threadIdx.x;
  __shared__ float r0[256], ys[256];
  r0[t] = Hall[(size_t)(b*256 + pc[b]-1)*256 + t];
  __syncthreads();
  const float* Cb = CIT + (size_t)tgt[b]*65536;
  float a = 0.f;
  for (int j=0;j<256;++j) a += Cb[j*256 + t] * r0[j];
  ys[t] = fmaxf(a, 0.f);
  __syncthreads();
  float a2 = 0.f;
  for (int i=0;i<256;++i) a2 += Wr[i*256 + t] * ys[i];
  RV[b*256 + t] = a2;
}

// ---------------- pooling ----------------
__global__ void k_pool(const float* __restrict__ X, const float* __restrict__ RV,
                       const float* __restrict__ Wg, u16* __restrict__ HB)
{
  int b = blockIdx.x, t = threadIdx.x;
  __shared__ float R[256], al[256], red[256], zp[256];
  R[t] = RV[b*256+t];
  __syncthreads();
  float sc = -3e38f;
  if (t < 255){
    const float* z = X + (size_t)(b*256+t)*256;
    float a=0.f;
    for (int d=0;d<256;++d) a += z[d]*R[d];
    sc = a;
  }
  red[t] = sc;
  __syncthreads();
  for (int s=128;s>0;s>>=1){ if (t<s) red[t]=fmaxf(red[t],red[t+s]); __syncthreads(); }
  float M = red[0];
  __syncthreads();
  float e = (t<255) ? __expf(sc - M) : 0.f;
  red[t] = e;
  __syncthreads();
  for (int s=128;s>0;s>>=1){ if (t<s) red[t]+=red[t+s]; __syncthreads(); }
  float S = red[0];
  al[t] = e / S;
  __syncthreads();
  float acc = 0.f;
  for (int p=0;p<255;++p) acc += al[p] * X[(size_t)(b*256+p)*256 + t];
  zp[t] = acc;
  __syncthreads();
  float a2 = 0.f;
  for (int d=0;d<256;++d) a2 += zp[d] * Wg[d*256 + t];
  for (int d=0;d<256;++d) a2 += R[d]  * Wg[(256+d)*256 + t];
  HB[b*256+t] = f2bf(fmaxf(a2, 0.f));
}

// ---------------- final vocab softmax ----------------
__global__ void k_osm(const float* __restrict__ LOG, float* __restrict__ out)
{
  int b = blockIdx.x, t = threadIdx.x;  // 512 threads
  __shared__ float red[512];
  const float* Lp = LOG + (size_t)b*30000;
  float mx = -3e38f;
  for (int i=t;i<30000;i+=512) mx = fmaxf(mx, Lp[i]);
  red[t]=mx; __syncthreads();
  for (int s=256;s>0;s>>=1){ if (t<s) red[t]=fmaxf(red[t],red[t+s]); __syncthreads(); }
  float M = red[0]; __syncthreads();
  float sm = 0.f;
  for (int i=t;i<30000;i+=512) sm += __expf(Lp[i]-M);
  red[t]=sm; __syncthreads();
  for (int s=256;s>0;s>>=1){ if (t<s) red[t]+=red[t+s]; __syncthreads(); }
  float rinv = 1.f/red[0];
  float* O = out + (size_t)b*30000;
  for (int i=t;i<30000;i+=512) O[i] = __expf(Lp[i]-M) * rinv;
}

// ---------------- host ----------------
extern "C" void kernel_launch(void* const* d_in, const int* in_sizes, int n_in,
                              void* d_out, int out_size, void* d_ws, size_t ws_size,
                              hipStream_t stream)
{
  const int*   tokens = (const int*)  d_in[0];
  const int*   pc     = (const int*)  d_in[1];
  const int*   tgt    = (const int*)  d_in[2];
  const float* emb    = (const float*)d_in[3];
  const float* l1k    = (const float*)d_in[4];
  const float* l1r    = (const float*)d_in[5];
  const float* l1b    = (const float*)d_in[6];
  const float* l2k    = (const float*)d_in[7];
  const float* l2r    = (const float*)d_in[8];
  const float* l2b    = (const float*)d_in[9];
  const float* wq     = (const float*)d_in[10];
  const float* wk     = (const float*)d_in[11];
  const float* wv     = (const float*)d_in[12];
  const float* wo     = (const float*)d_in[13];
  const float* ln1g   = (const float*)d_in[14];
  const float* ln1b   = (const float*)d_in[15];
  const float* w1e    = (const float*)d_in[16];
  const float* b1e    = (const float*)d_in[17];
  const float* w2e    = (const float*)d_in[18];
  const float* b2e    = (const float*)d_in[19];
  const float* ln2g   = (const float*)d_in[20];
  const float* ln2b   = (const float*)d_in[21];
  const float* Wr     = (const float*)d_in[22];
  const float* Wg     = (const float*)d_in[23];
  const float* Ci     = (const float*)d_in[24];

  char* ws = (char*)d_ws;
  u16*   EMBB = (u16*)  (ws + OFF_EMBB);
  u16*   WP1  = (u16*)  (ws + OFF_WP1);
  u16*   WP2  = (u16*)  (ws + OFF_WP2);
  float* CIT  = (float*)(ws + OFF_CIT);
  float* HALL = (float*)(ws + OFF_HALL);
  float* X    = (float*)(ws + OFF_X);
  u16*   XB   = (u16*)  (ws + OFF_XB);
  u16*   QKVb = (u16*)  (ws + OFF_QKV);
  u16*   AOb  = (u16*)  (ws + OFF_AO);
  u16*   Fb   = (u16*)  (ws + OFF_F);
  float* RV   = (float*)(ws + OFF_RV);
  u16*   HB   = (u16*)  (ws + OFF_HB);
  float* LOGp = (float*)(ws + OFF_LOG);
  u16*   H1A  = (u16*)  (ws + OFF_H1A);
  u16*   H1B  = (u16*)  (ws + OFF_H1B);
  u16*   H2A  = (u16*)  (ws + OFF_H2A);
  u16*   H2B  = (u16*)  (ws + OFF_H2B);
  u32*   BARC = (u32*)  (ws + OFF_BARC);

  PrepArgs pa;
  int ji = 0;
  auto addJ = [&](const float* s, size_t off, int K, int N, int stride, int f32o){
    pa.j[ji].src=s; pa.j[ji].dstOff=(u32)off; pa.j[ji].K=K; pa.j[ji].N=N; pa.j[ji].stride=stride; pa.j[ji].f32out=f32o; ++ji;
  };
  for (int l=0;l<4;++l) addJ(wq + l*65536,  OFF_BQKV + (size_t)(l*768      )*512, 256,256,256,0);
  for (int l=0;l<4;++l) addJ(wk + l*65536,  OFF_BQKV + (size_t)(l*768 + 256)*512, 256,256,256,0);
  for (int l=0;l<4;++l) addJ(wv + l*65536,  OFF_BQKV + (size_t)(l*768 + 512)*512, 256,256,256,0);
  for (int l=0;l<4;++l) addJ(wo + l*65536,  OFF_WOT  + (size_t)l*131072, 256,256,256,0);
  for (int l=0;l<4;++l) addJ(w1e + l*262144, OFF_W1ET + (size_t)l*524288, 256,1024,256,0);
  for (int l=0;l<4;++l) addJ(w2e + l*262144, OFF_W2ET + (size_t)l*524288, 1024,256,1024,0);
  for (int c=0;c<32;++c) addJ(Ci + (size_t)c*65536, OFF_CIT + (size_t)c*262144, 256,256,256,1);

  // zero h(-1) buffers + barrier arrival array
  hipMemsetAsync(ws + OFF_H1A, 0, 16777216 + 4096, stream);
  k_prep<<<dim3(256,56), dim3(256), 0, stream>>>(pa, ws);
  k_embcvt<<<dim3(7500), dim3(256), 0, stream>>>(emb, EMBB, 1920000);
  k_packfrag<<<dim3(256), dim3(256), 0, stream>>>(l1k, l1r, WP1);
  k_packfrag<<<dim3(256), dim3(256), 0, stream>>>(l2k, l2r, WP2);
  k_lstm3<<<dim3(256), dim3(1024), 0, stream>>>(tokens, EMBB, WP1, WP2, l1b, l2b,
                                                H1A, H1B, H2A, H2B, BARC, HALL);
  k_buildZ<<<dim3(2048), dim3(256), 0, stream>>>(HALL, pc, X, XB);
  k_rprep<<<dim3(32), dim3(256), 0, stream>>>(HALL, pc, tgt, CIT, Wr, RV);

  u16* BQKV = (u16*)(ws + OFF_BQKV);
  u16* WOT  = (u16*)(ws + OFF_WOT);
  u16* W1ET = (u16*)(ws + OFF_W1ET);
  u16* W2ET = (u16*)(ws + OFF_W2ET);
  for (int l=0;l<4;++l){
    k_gemm<64,0><<<dim3(128,3), dim3(512), 0, stream>>>(XB, BQKV + (size_t)l*768*256, QKVb, nullptr, nullptr, 8192, 768, 256, 768, nullptr, nullptr, nullptr);
    k_attn<<<dim3(256), dim3(256), 0, stream>>>(QKVb, AOb, pc);
    k_gemm<64,6><<<dim3(128,1), dim3(512), 0, stream>>>(AOb, WOT + (size_t)l*65536, X, nullptr, X, 8192, 256, 256, 256, ln1g + l*256, ln1b + l*256, XB);
    k_gemm<64,1><<<dim3(128,4), dim3(512), 0, stream>>>(XB, W1ET + (size_t)l*262144, Fb, b1e + l*1024, nullptr, 8192, 1024, 256, 1024, nullptr, nullptr, nullptr);
    k_gemm<64,7><<<dim3(128,1), dim3(512), 0, stream>>>(Fb, W2ET + (size_t)l*262144, X, b2e + l*256, X, 8192, 256, 1024, 256, ln2g + l*256, ln2b + l*256, XB);
  }

  k_pool<<<dim3(32), dim3(256), 0, stream>>>(X, RV, Wg, HB);
  k_gemm<32,4><<<dim3(1,118), dim3(512), 0, stream>>>(HB, EMBB, LOGp, nullptr, nullptr, 32, 30000, 256, 30000, nullptr, nullptr, nullptr);
  k_osm<<<dim3(32), dim3(512), 0, stream>>>(LOGp, (float*)d_out);
}

// Round 17
// 1953.371 us; speedup vs baseline: 1.1981x; 1.0367x over previous
//
#include <hip/hip_runtime.h>
#include <cstdint>
#include <cstddef>

typedef unsigned short u16;
typedef unsigned int   u32;
typedef float f32x4 __attribute__((ext_vector_type(4)));
typedef short s16x8 __attribute__((ext_vector_type(8)));
typedef u32   u32x4 __attribute__((ext_vector_type(4)));

#define DEV static __device__ __forceinline__
// wait + scheduling fence (rule #18: hipcc hoists reg-only MFMA past inline-asm waits)
#define WAIT0SB() do{ asm volatile("s_waitcnt vmcnt(0)" ::: "memory"); __builtin_amdgcn_sched_barrier(0); }while(0)

// ---------------- problem sizes ----------------
// B=32 P=256 L=32 V=30000 DE=DP=256 NH=8 DH=32 DFF=1024 NL=4, NSEQ=8192

// ---------------- ws layout (bytes) ----------------
static constexpr size_t OFF_EMBB = 0;            // bf16 [30000][256]
static constexpr size_t OFF_WP1  = 15360000;     // bf16 frag-packed [K1;R1] (1MB, 64 chunks x 16KB)
static constexpr size_t OFF_WP2  = 16408576;     // bf16 frag-packed [K2;R2] (1MB)
static constexpr size_t OFF_BQKV = 17457152;     // bf16 [4][768][256]
static constexpr size_t OFF_WOT  = 19030016;     // bf16 [4][256][256]
static constexpr size_t OFF_W1ET = 19554304;     // bf16 [4][1024][256]
static constexpr size_t OFF_W2ET = 21651456;     // bf16 [4][256][1024]
static constexpr size_t OFF_CIT  = 23748608;     // f32  [32][256][256] (C_i^T per mat)
static constexpr size_t OFF_HALL = 32137216;     // f32  [8192][256]
static constexpr size_t OFF_X    = 40525824;     // f32  [8192][256]
static constexpr size_t OFF_XB   = 48914432;     // bf16 [8192][256]
static constexpr size_t OFF_QKV  = 61497344;     // bf16 [8192][768]
static constexpr size_t OFF_AO   = 74080256;     // bf16 [8192][256]
static constexpr size_t OFF_F    = 78274560;     // bf16 [8192][1024]
static constexpr size_t OFF_RV   = 95051776;     // f32  [32][256]
static constexpr size_t OFF_HB   = 95084544;     // bf16 [32][256]
static constexpr size_t OFF_LOG  = 95100928;     // f32  [32][30000]
// LSTM h double-buffers + barrier table live in the dead X..RV region during k_lstm3
static constexpr size_t OFF_H1A  = OFF_X;                 // bf16 [8192][256] = 4MB
static constexpr size_t OFF_H1B  = OFF_X + 4194304;
static constexpr size_t OFF_H2A  = OFF_X + 8388608;
static constexpr size_t OFF_H2B  = OFF_X + 12582912;
static constexpr size_t OFF_BARC = OFF_X + 16777216;      // u32 arr[16][16] (per-sg barrier slots)

// ---------------- helpers ----------------
DEV u16 f2bf(float f){ u32 u = __builtin_bit_cast(u32, f); u += 0x7fffu + ((u>>16)&1u); return (u16)(u>>16); }
DEV float bf2f(u16 v){ return __builtin_bit_cast(float, (u32)v<<16); }
DEV float sigm(float x){ return 1.f/(1.f+__expf(-x)); }
DEV float tanh_f(float x){ float e=__expf(-2.f*fabsf(x)); float t=(1.f-e)/(1.f+e); return x<0.f? -t:t; }
DEV f32x4 splat4(float x){ f32x4 v={x,x,x,x}; return v; }
DEV f32x4 mfma16(s16x8 a, s16x8 b, f32x4 c){ return __builtin_amdgcn_mfma_f32_16x16x32_bf16(a,b,c,0,0,0); }

// XOR swizzles on 16B chunks within a row (row widths 256/128/32 bf16 elems)
DEV int swz256(int row, int col){ int ch=col>>3; return row*256 + (((ch ^ (row&7))&31)<<3) + (col&7); }
DEV int swz128(int row, int col){ int ch=col>>3; return row*128 + (((ch ^ (row&7))&15)<<3) + (col&7); }
DEV int swz32 (int row, int col){ int ch=col>>3; return row*32  + (((ch ^ (row&3))&3)<<3)  + (col&7); }

// ---------------- scope-explicit memory helpers (gfx940+ sc0/sc1 cpol; LLC scope ONLY —
// the XCD-L2-scope path is unvalidated and hung r14; never gate liveness on it) ----------------
DEV void st32_s(u32* p, u32 v){
  asm volatile("global_store_dword %0, %1, off sc0 sc1" :: "v"(p), "v"(v) : "memory");
}
DEV u32 ld32_s(const u32* p){
  u32 r;
  asm volatile("global_load_dword %0, %1, off sc0 sc1\n\ts_waitcnt vmcnt(0)" : "=v"(r) : "v"(p) : "memory");
  return r;
}
DEV void st16_s(u16* p, u16 v){
  asm volatile("global_store_short %0, %1, off sc0 sc1" :: "v"(p), "v"((u32)v) : "memory");
}
// issue 16 x 16B h-operand loads (two per-lane row addresses, 8 x 64B-offset each), NO wait.
DEV void ld16_iss(const u16* pa, const u16* pb, s16x8 r[16]){
  asm volatile(
    "global_load_dwordx4 %0, %16, off sc0 sc1\n\t"
    "global_load_dwordx4 %1, %16, off offset:64 sc0 sc1\n\t"
    "global_load_dwordx4 %2, %16, off offset:128 sc0 sc1\n\t"
    "global_load_dwordx4 %3, %16, off offset:192 sc0 sc1\n\t"
    "global_load_dwordx4 %4, %16, off offset:256 sc0 sc1\n\t"
    "global_load_dwordx4 %5, %16, off offset:320 sc0 sc1\n\t"
    "global_load_dwordx4 %6, %16, off offset:384 sc0 sc1\n\t"
    "global_load_dwordx4 %7, %16, off offset:448 sc0 sc1\n\t"
    "global_load_dwordx4 %8, %17, off sc0 sc1\n\t"
    "global_load_dwordx4 %9, %17, off offset:64 sc0 sc1\n\t"
    "global_load_dwordx4 %10, %17, off offset:128 sc0 sc1\n\t"
    "global_load_dwordx4 %11, %17, off offset:192 sc0 sc1\n\t"
    "global_load_dwordx4 %12, %17, off offset:256 sc0 sc1\n\t"
    "global_load_dwordx4 %13, %17, off offset:320 sc0 sc1\n\t"
    "global_load_dwordx4 %14, %17, off offset:384 sc0 sc1\n\t"
    "global_load_dwordx4 %15, %17, off offset:448 sc0 sc1"
    : "=&v"(r[0]),"=&v"(r[1]),"=&v"(r[2]),"=&v"(r[3]),
      "=&v"(r[4]),"=&v"(r[5]),"=&v"(r[6]),"=&v"(r[7]),
      "=&v"(r[8]),"=&v"(r[9]),"=&v"(r[10]),"=&v"(r[11]),
      "=&v"(r[12]),"=&v"(r[13]),"=&v"(r[14]),"=&v"(r[15])
    : "v"(pa), "v"(pb) : "memory");
}

// ---------------- per-sg 16-WG barrier (LLC sc0sc1 arrivals — the validated path).
// h-dataflow is strictly intra-sg (16 hs-WGs exchange slices of the same 512 seqs), so
// a per-sg barrier is semantically sufficient; decoupling the 16 sg-chains removes
// global skew compounding. All 256 WGs are co-resident (1 WG/CU, LDS-bound) -> live.
DEV void sgbar(u32* slots, int hs, u32 gen){
  __syncthreads();                       // every wave's h-stores drained (vmcnt 0) pre-arrival
  if (threadIdx.x==0){
    asm volatile("s_waitcnt vmcnt(0)" ::: "memory");
    st32_s(slots + hs, gen);
  }
  if (threadIdx.x < 64){
    bool done = false;
    do {
      u32 f = gen;
      if (threadIdx.x < 16) f = ld32_s(slots + threadIdx.x);
      done = __all(f >= gen);
      if (!done) __builtin_amdgcn_s_sleep(2);
    } while(!done);
  }
  __syncthreads();
}

// ---------------- prep: transposes (f32 -> bf16/f32, dst[n][k] = src[k][n]) ----------------
struct TJob { const float* src; u32 dstOff; int K; int N; int stride; int f32out; };
struct PrepArgs { TJob j[60]; };

__global__ void k_prep(PrepArgs pa, char* __restrict__ ws){
  TJob jb = pa.j[blockIdx.y];
  int tilesK = jb.K >> 5, tilesN = jb.N >> 5;
  int ti = blockIdx.x;
  if (ti >= tilesK*tilesN) return;
  int tk = ti % tilesK, tn = ti / tilesK;
  __shared__ float tile[32][33];
  int r = threadIdx.x >> 5, c = threadIdx.x & 31;
  #pragma unroll
  for (int rr=0; rr<32; rr+=8)
    tile[rr+r][c] = jb.src[(size_t)(tk*32+rr+r)*jb.N + tn*32 + c];
  __syncthreads();
  if (jb.f32out){
    float* dst = (float*)(ws + jb.dstOff);
    #pragma unroll
    for (int rr=0; rr<32; rr+=8)
      dst[(size_t)(tn*32+rr+r)*jb.stride + tk*32 + c] = tile[c][rr+r];
  } else {
    u16* dst = (u16*)(ws + jb.dstOff);
    #pragma unroll
    for (int rr=0; rr<32; rr+=8)
      dst[(size_t)(tn*32+rr+r)*jb.stride + tk*32 + c] = f2bf(tile[c][rr+r]);
  }
}

__global__ void k_embcvt(const float* __restrict__ src, u16* __restrict__ dst, int n4){
  int i = blockIdx.x*blockDim.x + threadIdx.x;
  if (i >= n4) return;
  float4 v = ((const float4*)src)[i];
  uint2 pk;
  pk.x = f2bf(v.x) | ((u32)f2bf(v.y)<<16);
  pk.y = f2bf(v.z) | ((u32)f2bf(v.w)<<16);
  ((uint2*)dst)[i] = pk;
}

// ---------------- fragment packer (64 chunks x [hs:16][lane:64] x 16B per layer) ----------------
__global__ void k_packfrag(const float* __restrict__ srcA, const float* __restrict__ srcB,
                           u16* __restrict__ dst)
{
  int gid = blockIdx.x*256 + threadIdx.x;   // 65536 total
  int lane = gid & 63;
  int hs   = (gid>>6) & 15;
  int c    = gid >> 10;                     // 0..63
  int kc = c>>2, g = c&3;
  int l4 = lane>>4, l15 = lane&15;
  int col = g*256 + hs*16 + l15;
  int k0  = kc*32 + l4*8;
  u16 out[8];
  #pragma unroll
  for (int j=0;j<8;++j){
    int k = k0 + j;
    float v = (k < 256) ? srcA[(size_t)k*1024 + col] : srcB[(size_t)(k-256)*1024 + col];
    out[j] = f2bf(v);
  }
  *(s16x8*)(dst + (size_t)gid*8) = *(const s16x8*)out;
}

// ---------------- persistent fused 2-layer LSTM (LDS weights, one per-sg LLC barrier
// per step, scattered LLC h-stores) ----------------
__global__ __launch_bounds__(1024,4) void k_lstm3(
    const int* __restrict__ tokens, const u16* __restrict__ EMBB,
    const u16* __restrict__ WP1, const u16* __restrict__ WP2,
    const float* __restrict__ b1, const float* __restrict__ b2,
    u16* __restrict__ H1A, u16* __restrict__ H1B,
    u16* __restrict__ H2A, u16* __restrict__ H2B,
    u32* __restrict__ bar, float* __restrict__ Hall)
{
  __shared__ u16 W1s[64*512];   // 64KB
  __shared__ u16 W2s[64*512];   // 64KB
  const int tid=threadIdx.x, lane=tid&63, v=tid>>6, l15=lane&15, l4=lane>>4;
  const int bid=blockIdx.x, sg=bid&15, hs=bid>>4;
  const int seq0w = sg*512 + v*32;
  u32* slots = bar + sg*16;

  #pragma unroll
  for (int i=0;i<4;++i){
    int c = v*4+i;
    const u16* s1 = WP1 + ((size_t)(c*16+hs))*512 + lane*8;
    const u16* s2 = WP2 + ((size_t)(c*16+hs))*512 + lane*8;
    __builtin_amdgcn_global_load_lds((const __attribute__((address_space(1))) void*)s1,
        (__attribute__((address_space(3))) void*)(W1s + c*512), 16, 0, 0);
    __builtin_amdgcn_global_load_lds((const __attribute__((address_space(1))) void*)s2,
        (__attribute__((address_space(3))) void*)(W2s + c*512), 16, 0, 0);
  }
  float bl1[4], bl2[4];
  #pragma unroll
  for (int g=0;g<4;++g){ bl1[g]=b1[g*256 + hs*16 + l15]; bl2[g]=b2[g*256 + hs*16 + l15]; }
  asm volatile("s_waitcnt vmcnt(0)" ::: "memory");
  __syncthreads();

  float c1[8], c2[8];
  #pragma unroll
  for (int i=0;i<8;++i){ c1[i]=0.f; c2[i]=0.f; }
  const int row0 = seq0w + l15, row1 = seq0w + 16 + l15;
  u32 gen = 0;

  #pragma unroll 1
  for (int t=0;t<32;++t){
    const u16* H1r = (t&1)? H1B : H1A;  u16* H1w = (t&1)? H1A : H1B;
    const u16* H2r = (t&1)? H2B : H2A;  u16* H2w = (t&1)? H2A : H2B;
    const int tok0 = tokens[row0*32 + t], tok1 = tokens[row1*32 + t];
    f32x4 acc[2][4];
    s16x8 r[16];
    // ---- layer 1: z1 = [e_t | h1(t-1)] @ [K1;R1] + b1 ----
    ld16_iss(H1r + (size_t)row0*256 + l4*8, H1r + (size_t)row1*256 + l4*8, r);
    #pragma unroll
    for (int g=0;g<4;++g){ acc[0][g]=splat4(bl1[g]); acc[1][g]=splat4(bl1[g]); }
    #pragma unroll
    for (int kc=0;kc<8;++kc){
      s16x8 fa0 = *(const s16x8*)(EMBB + (size_t)tok0*256 + kc*32 + l4*8);
      s16x8 fa1 = *(const s16x8*)(EMBB + (size_t)tok1*256 + kc*32 + l4*8);
      #pragma unroll
      for (int g=0;g<4;++g){
        s16x8 wf = *(const s16x8*)&W1s[(kc*4+g)*512 + lane*8];
        acc[0][g]=mfma16(fa0,wf,acc[0][g]);
        acc[1][g]=mfma16(fa1,wf,acc[1][g]);
      }
    }
    WAIT0SB();                                  // h1(t-1) operands landed (hidden under EMBB MFMAs)
    #pragma unroll
    for (int k2=0;k2<8;++k2){
      #pragma unroll
      for (int g=0;g<4;++g){
        s16x8 wf = *(const s16x8*)&W1s[((8+k2)*4+g)*512 + lane*8];
        acc[0][g]=mfma16(r[k2],wf,acc[0][g]);
        acc[1][g]=mfma16(r[8+k2],wf,acc[1][g]);
      }
    }
    #pragma unroll
    for (int m=0;m<2;++m)
      #pragma unroll
      for (int rr=0;rr<4;++rr){
        int idx=m*4+rr;
        float zi=acc[m][0][rr], zf=acc[m][1][rr], zg=acc[m][2][rr], zo=acc[m][3][rr];
        float cc=sigm(zf)*c1[idx]+sigm(zi)*tanh_f(zg);
        c1[idx]=cc;
        st16_s(H1w + (size_t)(seq0w + m*16 + l4*4 + rr)*256 + hs*16 + l15,
               f2bf(sigm(zo)*tanh_f(cc)));
      }
    ++gen; sgbar(slots, hs, gen);   // A(t): h1(t) visible; h2(t-1) (stored pre-barrier) visible
    // ---- layer 2: z2 = [h1(t) | h2(t-1)] @ [K2;R2] + b2 ----
    #pragma unroll
    for (int g=0;g<4;++g){ acc[0][g]=splat4(bl2[g]); acc[1][g]=splat4(bl2[g]); }
    ld16_iss(H1w + (size_t)row0*256 + l4*8, H1w + (size_t)row1*256 + l4*8, r);
    WAIT0SB();
    #pragma unroll
    for (int k2=0;k2<8;++k2){
      #pragma unroll
      for (int g=0;g<4;++g){
        s16x8 wf = *(const s16x8*)&W2s[(k2*4+g)*512 + lane*8];
        acc[0][g]=mfma16(r[k2],wf,acc[0][g]);
        acc[1][g]=mfma16(r[8+k2],wf,acc[1][g]);
      }
    }
    ld16_iss(H2r + (size_t)row0*256 + l4*8, H2r + (size_t)row1*256 + l4*8, r);
    WAIT0SB();
    #pragma unroll
    for (int k2=0;k2<8;++k2){
      #pragma unroll
      for (int g=0;g<4;++g){
        s16x8 wf = *(const s16x8*)&W2s[((8+k2)*4+g)*512 + lane*8];
        acc[0][g]=mfma16(r[k2],wf,acc[0][g]);
        acc[1][g]=mfma16(r[8+k2],wf,acc[1][g]);
      }
    }
    #pragma unroll
    for (int m=0;m<2;++m)
      #pragma unroll
      for (int rr=0;rr<4;++rr){
        int idx=m*4+rr;
        float zi=acc[m][0][rr], zf=acc[m][1][rr], zg=acc[m][2][rr], zo=acc[m][3][rr];
        float cc=sigm(zf)*c2[idx]+sigm(zi)*tanh_f(zg);
        c2[idx]=cc;
        float h=sigm(zo)*tanh_f(cc);
        st16_s(H2w + (size_t)(seq0w + m*16 + l4*4 + rr)*256 + hs*16 + l15, f2bf(h));
        if (t==31) Hall[(size_t)(seq0w + m*16 + l4*4 + rr)*256 + hs*16 + l15] = h;
      }
    // no barrier here: h2(t) publishes at A(t+1); kernel end syncs t=31
  }
}

// ---------------- generic bf16 GEMM: C[M][N] = A[M][K] @ Bt[N][K]^T ----------------
// EPI: 0 bf16; 1 +bias,relu,bf16; 4 f32 (guards); 5 +bias,bf16,M-guard;
//      6 +Res, LayerNorm -> X f32 + XB bf16 (N==256, full rows per block)
//      7 +bias +Res, LayerNorm -> X f32 + XB bf16
template<int BM, int EPI>
__global__ __launch_bounds__(512,2) void k_gemm(
    const u16* __restrict__ A, const u16* __restrict__ Bt, void* __restrict__ Cv,
    const float* __restrict__ bias, const float* __restrict__ Res,
    int M, int N, int K, int ldC,
    const float* __restrict__ lng, const float* __restrict__ lnb, u16* __restrict__ outB)
{
  __shared__ u16 Asl[BM*256];
  __shared__ float sS[512];
  __shared__ float sQ[512];
  const int tid=threadIdx.x, lane=tid&63, w=tid>>6, l15=lane&15, l4=lane>>4;
  const int mb=blockIdx.x, nb=blockIdx.y;
  constexpr int MT = BM/16;
  const int col0 = nb*256 + w*32;
  float bz0=0.f, bz1=0.f;
  if (EPI==1 || EPI==5 || EPI==7){ bz0 = bias[col0 + l15]; bz1 = bias[col0 + 16 + l15]; }
  f32x4 acc[MT][2];
  #pragma unroll
  for (int mt=0;mt<MT;++mt){ acc[mt][0]=splat4(bz0); acc[mt][1]=splat4(bz1); }
  for (int kb=0; kb<K; kb+=256){
    __syncthreads();
    if (tid < BM*8){
      int row=tid>>3, part=tid&7;
      int arow = mb*BM+row; if (arow > M-1) arow = M-1;
      const u16* src = A + (size_t)arow*K + kb + part*32;
      #pragma unroll
      for (int i=0;i<4;++i)
        *(s16x8*)&Asl[swz256(row, part*32+i*8)] = *(const s16x8*)(src+i*8);
    }
    __syncthreads();
    #pragma unroll
    for (int kc=0; kc<8; ++kc){
      s16x8 fa[MT];
      #pragma unroll
      for (int mt=0;mt<MT;++mt)
        fa[mt] = *(const s16x8*)&Asl[swz256(mt*16+l15, kc*32 + l4*8)];
      #pragma unroll
      for (int n=0;n<2;++n){
        int brow = col0 + n*16 + l15; if (brow > N-1) brow = N-1;
        const s16x8 fb = *(const s16x8*)(Bt + (size_t)brow*K + kb + kc*32 + l4*8);
        #pragma unroll
        for (int mt=0;mt<MT;++mt) acc[mt][n] = mfma16(fa[mt], fb, acc[mt][n]);
      }
    }
  }
  if constexpr (EPI==6 || EPI==7){
    // fused residual + LayerNorm; block holds full rows (N=256).
    float vv[MT][2][4];
    #pragma unroll
    for (int mt=0;mt<MT;++mt)
      #pragma unroll
      for (int n=0;n<2;++n)
        #pragma unroll
        for (int r=0;r<4;++r){
          int row = mb*BM + mt*16 + l4*4 + r;
          int col = col0 + n*16 + l15;
          vv[mt][n][r] = acc[mt][n][r] + Res[(size_t)row*256 + col];
        }
    #pragma unroll
    for (int mt=0;mt<MT;++mt)
      #pragma unroll
      for (int r=0;r<4;++r){
        float s = vv[mt][0][r] + vv[mt][1][r];
        float q = vv[mt][0][r]*vv[mt][0][r] + vv[mt][1][r]*vv[mt][1][r];
        #pragma unroll
        for (int msk=1;msk<16;msk<<=1){ s += __shfl_xor(s, msk, 64); q += __shfl_xor(q, msk, 64); }
        if (l15==0){ sS[w*64 + mt*16 + l4*4 + r] = s; sQ[w*64 + mt*16 + l4*4 + r] = q; }
      }
    __syncthreads();
    #pragma unroll
    for (int mt=0;mt<MT;++mt)
      #pragma unroll
      for (int r=0;r<4;++r){
        int lrow = mt*16 + l4*4 + r;
        float S=0.f, Q=0.f;
        #pragma unroll
        for (int w2=0;w2<8;++w2){ S += sS[w2*64 + lrow]; Q += sQ[w2*64 + lrow]; }
        float mean = S * (1.f/256.f);
        float var  = Q * (1.f/256.f) - mean*mean;
        float rstd = rsqrtf(var + 1e-5f);
        int row = mb*BM + lrow;
        #pragma unroll
        for (int n=0;n<2;++n){
          int col = col0 + n*16 + l15;
          float ov = (vv[mt][n][r]-mean)*rstd*lng[col] + lnb[col];
          ((float*)Cv)[(size_t)row*256 + col] = ov;
          outB[(size_t)row*256 + col] = f2bf(ov);
        }
      }
  } else {
    #pragma unroll
    for (int mt=0;mt<MT;++mt){
      #pragma unroll
      for (int n=0;n<2;++n){
        #pragma unroll
        for (int r=0;r<4;++r){
          int row = mb*BM + mt*16 + l4*4 + r;
          int col = col0 + n*16 + l15;
          if (col < N && row < M){
            float v = acc[mt][n][r];
            if (EPI==0){ ((u16*)Cv)[(size_t)row*ldC + col] = f2bf(v); }
            else if (EPI==1){ ((u16*)Cv)[(size_t)row*ldC + col] = f2bf(fmaxf(v,0.f)); }
            else if (EPI==5){ ((u16*)Cv)[(size_t)row*ldC + col] = f2bf(v); }
            else { ((float*)Cv)[(size_t)row*ldC + col] = v; }
          }
        }
      }
    }
  }
}

// ---------------- attention, one WG per (b,h) ----------------
__global__ __launch_bounds__(256) void k_attn(const u16* __restrict__ QKV, u16* __restrict__ AO,
                                              const int* __restrict__ pc)
{
  __shared__ u16 Qs[256*32];
  __shared__ u16 Ks[256*32];
  __shared__ u16 Vt[32*256];
  __shared__ u16 Ab[4][64*128];
  const int bh=blockIdx.x, b=bh>>3, h=bh&7;
  const int tid=threadIdx.x, lane=tid&63, w=tid>>6, l15=lane&15, l4=lane>>4;
  const int pcm1 = pc[b]-1;
  {
    int row = tid;
    const u16* base = QKV + (size_t)(b*256+row)*768 + h*32;
    #pragma unroll
    for (int i=0;i<4;++i){
      *(s16x8*)&Qs[swz32(row, i*8)] = *(const s16x8*)(base + i*8);
      *(s16x8*)&Ks[swz32(row, i*8)] = *(const s16x8*)(base + 256 + i*8);
    }
    #pragma unroll
    for (int i=0;i<4;++i){
      s16x8 v = *(const s16x8*)(base + 512 + i*8);
      #pragma unroll
      for (int j=0;j<8;++j){
        int d = i*8+j;
        Vt[d*256 + ((((row>>3) ^ (d&7))&31)<<3) + (row&7)] = (u16)v[j];
      }
    }
  }
  __syncthreads();
  const float scale = 0.17677669529663689f;
  const int q0w = w*64;
  float rmax[4][4], rinv[4][4];
  #pragma unroll 1
  for (int m=0;m<4;++m){
    f32x4 sacc[16];
    #pragma unroll
    for (int nt=0;nt<16;++nt) sacc[nt]=splat4(0.f);
    s16x8 fa = *(const s16x8*)&Qs[swz32(q0w+m*16+l15, l4*8)];
    #pragma unroll
    for (int nt=0;nt<16;++nt){
      s16x8 fb = *(const s16x8*)&Ks[swz32(nt*16+l15, l4*8)];
      sacc[nt] = mfma16(fa, fb, sacc[nt]);
    }
    #pragma unroll
    for (int r=0;r<4;++r){
      int q = q0w + m*16 + l4*4 + r;
      bool vq = q < pcm1;
      float sv[16]; float mx = -3e38f;
      #pragma unroll
      for (int nt=0;nt<16;++nt){
        int k = nt*16 + l15;
        float s = (vq && k < pcm1) ? sacc[nt][r]*scale : -1e9f;
        if (k == 255) s = -1e30f;
        sv[nt] = s; mx = fmaxf(mx, s);
      }
      #pragma unroll
      for (int msk=1;msk<16;msk<<=1) mx = fmaxf(mx, __shfl_xor(mx, msk, 64));
      float sum = 0.f;
      #pragma unroll
      for (int nt=0;nt<16;++nt) sum += __expf(sv[nt]-mx);
      #pragma unroll
      for (int msk=1;msk<16;msk<<=1) sum += __shfl_xor(sum, msk, 64);
      rmax[m][r]=mx; rinv[m][r]=1.f/sum;
    }
  }
  f32x4 oacc[4][2];
  #pragma unroll
  for (int m=0;m<4;++m){ oacc[m][0]=splat4(0.f); oacc[m][1]=splat4(0.f); }
  #pragma unroll 1
  for (int kg=0; kg<2; ++kg){
    #pragma unroll 1
    for (int m=0;m<4;++m){
      s16x8 fa = *(const s16x8*)&Qs[swz32(q0w+m*16+l15, l4*8)];
      #pragma unroll
      for (int nt2=0;nt2<8;++nt2){
        int nt = kg*8 + nt2;
        s16x8 fb = *(const s16x8*)&Ks[swz32(nt*16+l15, l4*8)];
        f32x4 sa = mfma16(fa, fb, splat4(0.f));
        #pragma unroll
        for (int r=0;r<4;++r){
          int q = q0w + m*16 + l4*4 + r;
          int k = nt*16 + l15;
          float s = (q < pcm1 && k < pcm1) ? sa[r]*scale : -1e9f;
          if (k == 255) s = -1e30f;
          float p = __expf(s - rmax[m][r]) * rinv[m][r];
          Ab[w][swz128(m*16 + l4*4 + r, nt2*16 + l15)] = f2bf(p);
        }
      }
    }
    #pragma unroll 1
    for (int m=0;m<4;++m){
      #pragma unroll
      for (int kc=0;kc<4;++kc){
        s16x8 fa2 = *(const s16x8*)&Ab[w][swz128(m*16+l15, kc*32 + l4*8)];
        #pragma unroll
        for (int n=0;n<2;++n){
          int d = n*16 + l15;
          int kch = kg*16 + kc*4 + l4;
          s16x8 fb = *(const s16x8*)&Vt[d*256 + (((kch ^ (d&7))&31)<<3)];
          oacc[m][n] = mfma16(fa2, fb, oacc[m][n]);
        }
      }
    }
  }
  #pragma unroll
  for (int m=0;m<4;++m){
    #pragma unroll
    for (int n=0;n<2;++n){
      #pragma unroll
      for (int r=0;r<4;++r){
        int q = q0w + m*16 + l4*4 + r;
        AO[(size_t)(b*256+q)*256 + h*32 + n*16 + l15] = f2bf(oacc[m][n][r]);
      }
    }
  }
}

// ---------------- build masked encoder input ----------------
__global__ void k_buildZ(const float* __restrict__ Hall, const int* __restrict__ pc,
                         float* __restrict__ X, u16* __restrict__ Xb)
{
  int gid = blockIdx.x*256 + threadIdx.x;   // float4 id, 524288 total
  int row = gid >> 6;
  int b = row >> 8, p = row & 255;
  float4 v; v.x=v.y=v.z=v.w=0.f;
  if (p < pc[b]-1) v = ((const float4*)Hall)[gid];
  ((float4*)X)[gid] = v;
  uint2 pk; pk.x = f2bf(v.x) | ((u32)f2bf(v.y)<<16); pk.y = f2bf(v.z) | ((u32)f2bf(v.w)<<16);
  ((uint2*)Xb)[gid] = pk;
}

// ---------------- R vector: R = relu(C_i[tgt] @ R0) @ W_r ----------------
__global__ void k_rprep(const float* __restrict__ Hall, const int* __restrict__ pc, const int* __restrict__ tgt,
                        const float* __restrict__ CIT, const float* __restrict__ Wr, float* __restrict__ RV)
{
  int b = blockIdx.x, t = threadIdx.x;
  __shared__ float r0[256], ys[256];
  r0[t] = Hall[(size_t)(b*256 + pc[b]-1)*256 + t];
  __syncthreads();
  const float* Cb = CIT + (size_t)tgt[b]*65536;
  float a = 0.f;
  for (int j=0;j<256;++j) a += Cb[j*256 + t] * r0[j];
  ys[t] = fmaxf(a, 0.f);
  __syncthreads();
  float a2 = 0.f;
  for (int i=0;i<256;++i) a2 += Wr[i*256 + t] * ys[i];
  RV[b*256 + t] = a2;
}

// ---------------- pooling ----------------
__global__ void k_pool(const float* __restrict__ X, const float* __restrict__ RV,
                       const float* __restrict__ Wg, u16* __restrict__ HB)
{
  int b = blockIdx.x, t = threadIdx.x;
  __shared__ float R[256], al[256], red[256], zp[256];
  R[t] = RV[b*256+t];
  __syncthreads();
  float sc = -3e38f;
  if (t < 255){
    const float* z = X + (size_t)(b*256+t)*256;
    float a=0.f;
    for (int d=0;d<256;++d) a += z[d]*R[d];
    sc = a;
  }
  red[t] = sc;
  __syncthreads();
  for (int s=128;s>0;s>>=1){ if (t<s) red[t]=fmaxf(red[t],red[t+s]); __syncthreads(); }
  float M = red[0];
  __syncthreads();
  float e = (t<255) ? __expf(sc - M) : 0.f;
  red[t] = e;
  __syncthreads();
  for (int s=128;s>0;s>>=1){ if (t<s) red[t]+=red[t+s]; __syncthreads(); }
  float S = red[0];
  al[t] = e / S;
  __syncthreads();
  float acc = 0.f;
  for (int p=0;p<255;++p) acc += al[p] * X[(size_t)(b*256+p)*256 + t];
  zp[t] = acc;
  __syncthreads();
  float a2 = 0.f;
  for (int d=0;d<256;++d) a2 += zp[d] * Wg[d*256 + t];
  for (int d=0;d<256;++d) a2 += R[d]  * Wg[(256+d)*256 + t];
  HB[b*256+t] = f2bf(fmaxf(a2, 0.f));
}

// ---------------- final vocab softmax ----------------
__global__ void k_osm(const float* __restrict__ LOG, float* __restrict__ out)
{
  int b = blockIdx.x, t = threadIdx.x;  // 512 threads
  __shared__ float red[512];
  const float* Lp = LOG + (size_t)b*30000;
  float mx = -3e38f;
  for (int i=t;i<30000;i+=512) mx = fmaxf(mx, Lp[i]);
  red[t]=mx; __syncthreads();
  for (int s=256;s>0;s>>=1){ if (t<s) red[t]=fmaxf(red[t],red[t+s]); __syncthreads(); }
  float M = red[0]; __syncthreads();
  float sm = 0.f;
  for (int i=t;i<30000;i+=512) sm += __expf(Lp[i]-M);
  red[t]=sm; __syncthreads();
  for (int s=256;s>0;s>>=1){ if (t<s) red[t]+=red[t+s]; __syncthreads(); }
  float rinv = 1.f/red[0];
  float* O = out + (size_t)b*30000;
  for (int i=t;i<30000;i+=512) O[i] = __expf(Lp[i]-M) * rinv;
}

// ---------------- host ----------------
extern "C" void kernel_launch(void* const* d_in, const int* in_sizes, int n_in,
                              void* d_out, int out_size, void* d_ws, size_t ws_size,
                              hipStream_t stream)
{
  const int*   tokens = (const int*)  d_in[0];
  const int*   pc     = (const int*)  d_in[1];
  const int*   tgt    = (const int*)  d_in[2];
  const float* emb    = (const float*)d_in[3];
  const float* l1k    = (const float*)d_in[4];
  const float* l1r    = (const float*)d_in[5];
  const float* l1b    = (const float*)d_in[6];
  const float* l2k    = (const float*)d_in[7];
  const float* l2r    = (const float*)d_in[8];
  const float* l2b    = (const float*)d_in[9];
  const float* wq     = (const float*)d_in[10];
  const float* wk     = (const float*)d_in[11];
  const float* wv     = (const float*)d_in[12];
  const float* wo     = (const float*)d_in[13];
  const float* ln1g   = (const float*)d_in[14];
  const float* ln1b   = (const float*)d_in[15];
  const float* w1e    = (const float*)d_in[16];
  const float* b1e    = (const float*)d_in[17];
  const float* w2e    = (const float*)d_in[18];
  const float* b2e    = (const float*)d_in[19];
  const float* ln2g   = (const float*)d_in[20];
  const float* ln2b   = (const float*)d_in[21];
  const float* Wr     = (const float*)d_in[22];
  const float* Wg     = (const float*)d_in[23];
  const float* Ci     = (const float*)d_in[24];

  char* ws = (char*)d_ws;
  u16*   EMBB = (u16*)  (ws + OFF_EMBB);
  u16*   WP1  = (u16*)  (ws + OFF_WP1);
  u16*   WP2  = (u16*)  (ws + OFF_WP2);
  float* CIT  = (float*)(ws + OFF_CIT);
  float* HALL = (float*)(ws + OFF_HALL);
  float* X    = (float*)(ws + OFF_X);
  u16*   XB   = (u16*)  (ws + OFF_XB);
  u16*   QKVb = (u16*)  (ws + OFF_QKV);
  u16*   AOb  = (u16*)  (ws + OFF_AO);
  u16*   Fb   = (u16*)  (ws + OFF_F);
  float* RV   = (float*)(ws + OFF_RV);
  u16*   HB   = (u16*)  (ws + OFF_HB);
  float* LOGp = (float*)(ws + OFF_LOG);
  u16*   H1A  = (u16*)  (ws + OFF_H1A);
  u16*   H1B  = (u16*)  (ws + OFF_H1B);
  u16*   H2A  = (u16*)  (ws + OFF_H2A);
  u16*   H2B  = (u16*)  (ws + OFF_H2B);
  u32*   BARC = (u32*)  (ws + OFF_BARC);

  PrepArgs pa;
  int ji = 0;
  auto addJ = [&](const float* s, size_t off, int K, int N, int stride, int f32o){
    pa.j[ji].src=s; pa.j[ji].dstOff=(u32)off; pa.j[ji].K=K; pa.j[ji].N=N; pa.j[ji].stride=stride; pa.j[ji].f32out=f32o; ++ji;
  };
  for (int l=0;l<4;++l) addJ(wq + l*65536,  OFF_BQKV + (size_t)(l*768      )*512, 256,256,256,0);
  for (int l=0;l<4;++l) addJ(wk + l*65536,  OFF_BQKV + (size_t)(l*768 + 256)*512, 256,256,256,0);
  for (int l=0;l<4;++l) addJ(wv + l*65536,  OFF_BQKV + (size_t)(l*768 + 512)*512, 256,256,256,0);
  for (int l=0;l<4;++l) addJ(wo + l*65536,  OFF_WOT  + (size_t)l*131072, 256,256,256,0);
  for (int l=0;l<4;++l) addJ(w1e + l*262144, OFF_W1ET + (size_t)l*524288, 256,1024,256,0);
  for (int l=0;l<4;++l) addJ(w2e + l*262144, OFF_W2ET + (size_t)l*524288, 1024,256,1024,0);
  for (int c=0;c<32;++c) addJ(Ci + (size_t)c*65536, OFF_CIT + (size_t)c*262144, 256,256,256,1);

  // zero h(-1) buffers + barrier slot array
  hipMemsetAsync(ws + OFF_H1A, 0, 16777216 + 4096, stream);
  k_prep<<<dim3(256,56), dim3(256), 0, stream>>>(pa, ws);
  k_embcvt<<<dim3(7500), dim3(256), 0, stream>>>(emb, EMBB, 1920000);
  k_packfrag<<<dim3(256), dim3(256), 0, stream>>>(l1k, l1r, WP1);
  k_packfrag<<<dim3(256), dim3(256), 0, stream>>>(l2k, l2r, WP2);
  k_lstm3<<<dim3(256), dim3(1024), 0, stream>>>(tokens, EMBB, WP1, WP2, l1b, l2b,
                                                H1A, H1B, H2A, H2B, BARC, HALL);
  k_buildZ<<<dim3(2048), dim3(256), 0, stream>>>(HALL, pc, X, XB);
  k_rprep<<<dim3(32), dim3(256), 0, stream>>>(HALL, pc, tgt, CIT, Wr, RV);

  u16* BQKV = (u16*)(ws + OFF_BQKV);
  u16* WOT  = (u16*)(ws + OFF_WOT);
  u16* W1ET = (u16*)(ws + OFF_W1ET);
  u16* W2ET = (u16*)(ws + OFF_W2ET);
  for (int l=0;l<4;++l){
    k_gemm<64,0><<<dim3(128,3), dim3(512), 0, stream>>>(XB, BQKV + (size_t)l*768*256, QKVb, nullptr, nullptr, 8192, 768, 256, 768, nullptr, nullptr, nullptr);
    k_attn<<<dim3(256), dim3(256), 0, stream>>>(QKVb, AOb, pc);
    k_gemm<64,6><<<dim3(128,1), dim3(512), 0, stream>>>(AOb, WOT + (size_t)l*65536, X, nullptr, X, 8192, 256, 256, 256, ln1g + l*256, ln1b + l*256, XB);
    k_gemm<64,1><<<dim3(128,4), dim3(512), 0, stream>>>(XB, W1ET + (size_t)l*262144, Fb, b1e + l*1024, nullptr, 8192, 1024, 256, 1024, nullptr, nullptr, nullptr);
    k_gemm<64,7><<<dim3(128,1), dim3(512), 0, stream>>>(Fb, W2ET + (size_t)l*262144, X, b2e + l*256, X, 8192, 256, 1024, 256, ln2g + l*256, ln2b + l*256, XB);
  }

  k_pool<<<dim3(32), dim3(256), 0, stream>>>(X, RV, Wg, HB);
  k_gemm<32,4><<<dim3(1,118), dim3(512), 0, stream>>>(HB, EMBB, LOGp, nullptr, nullptr, 32, 30000, 256, 30000, nullptr, nullptr, nullptr);
  k_osm<<<dim3(32), dim3(512), 0, stream>>>(LOGp, (float*)d_out);
}

// Round 18
// 1941.688 us; speedup vs baseline: 1.2053x; 1.0060x over previous
//
#include <hip/hip_runtime.h>
#include <cstdint>
#include <cstddef>

typedef unsigned short u16;
typedef unsigned int   u32;
typedef float f32x4 __attribute__((ext_vector_type(4)));
typedef short s16x8 __attribute__((ext_vector_type(8)));
typedef u32   u32x4 __attribute__((ext_vector_type(4)));

#define DEV static __device__ __forceinline__
// wait + scheduling fence (rule #18: hipcc hoists reg-only MFMA past inline-asm waits)
#define WAIT0SB() do{ asm volatile("s_waitcnt vmcnt(0)" ::: "memory"); __builtin_amdgcn_sched_barrier(0); }while(0)

// ---------------- problem sizes ----------------
// B=32 P=256 L=32 V=30000 DE=DP=256 NH=8 DH=32 DFF=1024 NL=4, NSEQ=8192

// ---------------- ws layout (bytes) ----------------
static constexpr size_t OFF_EMBB = 0;            // bf16 [30000][256]
static constexpr size_t OFF_WP1  = 15360000;     // bf16 frag-packed [K1;R1] (1MB, 64 chunks x 16KB)
static constexpr size_t OFF_WP2  = 16408576;     // bf16 frag-packed [K2;R2] (1MB)
static constexpr size_t OFF_BQKV = 17457152;     // bf16 [4][768][256]
static constexpr size_t OFF_WOT  = 19030016;     // bf16 [4][256][256]
static constexpr size_t OFF_W1ET = 19554304;     // bf16 [4][1024][256]
static constexpr size_t OFF_W2ET = 21651456;     // bf16 [4][256][1024]
static constexpr size_t OFF_CIT  = 23748608;     // f32  [32][256][256] (C_i^T per mat)
static constexpr size_t OFF_HALL = 32137216;     // f32  [8192][256]
static constexpr size_t OFF_X    = 40525824;     // f32  [8192][256]
static constexpr size_t OFF_XB   = 48914432;     // bf16 [8192][256]
static constexpr size_t OFF_QKV  = 61497344;     // bf16 [8192][768]
static constexpr size_t OFF_AO   = 74080256;     // bf16 [8192][256]
static constexpr size_t OFF_F    = 78274560;     // bf16 [8192][1024]
static constexpr size_t OFF_RV   = 95051776;     // f32  [32][256]
static constexpr size_t OFF_HB   = 95084544;     // bf16 [32][256]
static constexpr size_t OFF_LOG  = 95100928;     // f32  [32][30000]
// LSTM h double-buffers + barrier table live in the dead X..RV region during k_lstm3
static constexpr size_t OFF_H1A  = OFF_X;                 // bf16 [8192][256] = 4MB
static constexpr size_t OFF_H1B  = OFF_X + 4194304;
static constexpr size_t OFF_H2A  = OFF_X + 8388608;
static constexpr size_t OFF_H2B  = OFF_X + 12582912;
static constexpr size_t OFF_BARC = OFF_X + 16777216;      // u32 arr[16][16] (per-sg barrier slots)

// ---------------- helpers ----------------
DEV u16 f2bf(float f){ u32 u = __builtin_bit_cast(u32, f); u += 0x7fffu + ((u>>16)&1u); return (u16)(u>>16); }
DEV float bf2f(u16 v){ return __builtin_bit_cast(float, (u32)v<<16); }
DEV float sigm(float x){ return 1.f/(1.f+__expf(-x)); }
DEV float tanh_f(float x){ float e=__expf(-2.f*fabsf(x)); float t=(1.f-e)/(1.f+e); return x<0.f? -t:t; }
DEV f32x4 splat4(float x){ f32x4 v={x,x,x,x}; return v; }
DEV f32x4 mfma16(s16x8 a, s16x8 b, f32x4 c){ return __builtin_amdgcn_mfma_f32_16x16x32_bf16(a,b,c,0,0,0); }

// XOR swizzles on 16B chunks within a row (row widths 256/128/32 bf16 elems)
DEV int swz256(int row, int col){ int ch=col>>3; return row*256 + (((ch ^ (row&7))&31)<<3) + (col&7); }
DEV int swz128(int row, int col){ int ch=col>>3; return row*128 + (((ch ^ (row&7))&15)<<3) + (col&7); }
DEV int swz32 (int row, int col){ int ch=col>>3; return row*32  + (((ch ^ (row&3))&3)<<3)  + (col&7); }

// ---------------- scope-explicit memory helpers ----------------
// gfx940+ cpol encodes SCOPE: {}=CU, sc0=SE, sc1=DEVICE, sc0+sc1=SYSTEM.
// r12-r17 used SYSTEM scope -> bypasses Infinity Cache -> all h-exchange at HBM
// (FETCH_SIZE 1.45GB/dispatch = 45MB/step of HBM reads confirmed). DEVICE scope (sc1)
// is sufficient for cross-XCD coherence (G16) and is served/cached by the 256MB LLC.
DEV void st32_s(u32* p, u32 v){
  asm volatile("global_store_dword %0, %1, off sc1" :: "v"(p), "v"(v) : "memory");
}
DEV u32 ld32_s(const u32* p){
  u32 r;
  asm volatile("global_load_dword %0, %1, off sc1\n\ts_waitcnt vmcnt(0)" : "=v"(r) : "v"(p) : "memory");
  return r;
}
DEV void st16_s(u16* p, u16 v){
  asm volatile("global_store_short %0, %1, off sc1" :: "v"(p), "v"((u32)v) : "memory");
}
// issue 16 x 16B h-operand loads (two per-lane row addresses, 8 x 64B-offset each), NO wait.
DEV void ld16_iss(const u16* pa, const u16* pb, s16x8 r[16]){
  asm volatile(
    "global_load_dwordx4 %0, %16, off sc1\n\t"
    "global_load_dwordx4 %1, %16, off offset:64 sc1\n\t"
    "global_load_dwordx4 %2, %16, off offset:128 sc1\n\t"
    "global_load_dwordx4 %3, %16, off offset:192 sc1\n\t"
    "global_load_dwordx4 %4, %16, off offset:256 sc1\n\t"
    "global_load_dwordx4 %5, %16, off offset:320 sc1\n\t"
    "global_load_dwordx4 %6, %16, off offset:384 sc1\n\t"
    "global_load_dwordx4 %7, %16, off offset:448 sc1\n\t"
    "global_load_dwordx4 %8, %17, off sc1\n\t"
    "global_load_dwordx4 %9, %17, off offset:64 sc1\n\t"
    "global_load_dwordx4 %10, %17, off offset:128 sc1\n\t"
    "global_load_dwordx4 %11, %17, off offset:192 sc1\n\t"
    "global_load_dwordx4 %12, %17, off offset:256 sc1\n\t"
    "global_load_dwordx4 %13, %17, off offset:320 sc1\n\t"
    "global_load_dwordx4 %14, %17, off offset:384 sc1\n\t"
    "global_load_dwordx4 %15, %17, off offset:448 sc1"
    : "=&v"(r[0]),"=&v"(r[1]),"=&v"(r[2]),"=&v"(r[3]),
      "=&v"(r[4]),"=&v"(r[5]),"=&v"(r[6]),"=&v"(r[7]),
      "=&v"(r[8]),"=&v"(r[9]),"=&v"(r[10]),"=&v"(r[11]),
      "=&v"(r[12]),"=&v"(r[13]),"=&v"(r[14]),"=&v"(r[15])
    : "v"(pa), "v"(pb) : "memory");
}

// ---------------- per-sg 16-WG barrier (device-scope arrivals in LLC).
// h-dataflow is strictly intra-sg (16 hs-WGs exchange slices of the same 512 seqs), so
// a per-sg barrier is semantically sufficient. All 256 WGs co-resident (1 WG/CU) -> live.
DEV void sgbar(u32* slots, int hs, u32 gen){
  __syncthreads();                       // every wave's h-stores drained (vmcnt 0) pre-arrival
  if (threadIdx.x==0){
    asm volatile("s_waitcnt vmcnt(0)" ::: "memory");
    st32_s(slots + hs, gen);
  }
  if (threadIdx.x < 64){
    bool done = false;
    do {
      u32 f = gen;
      if (threadIdx.x < 16) f = ld32_s(slots + threadIdx.x);
      done = __all(f >= gen);
      if (!done) __builtin_amdgcn_s_sleep(2);
    } while(!done);
  }
  __syncthreads();
}

// ---------------- prep: transposes (f32 -> bf16/f32, dst[n][k] = src[k][n]) ----------------
struct TJob { const float* src; u32 dstOff; int K; int N; int stride; int f32out; };
struct PrepArgs { TJob j[60]; };

__global__ void k_prep(PrepArgs pa, char* __restrict__ ws){
  TJob jb = pa.j[blockIdx.y];
  int tilesK = jb.K >> 5, tilesN = jb.N >> 5;
  int ti = blockIdx.x;
  if (ti >= tilesK*tilesN) return;
  int tk = ti % tilesK, tn = ti / tilesK;
  __shared__ float tile[32][33];
  int r = threadIdx.x >> 5, c = threadIdx.x & 31;
  #pragma unroll
  for (int rr=0; rr<32; rr+=8)
    tile[rr+r][c] = jb.src[(size_t)(tk*32+rr+r)*jb.N + tn*32 + c];
  __syncthreads();
  if (jb.f32out){
    float* dst = (float*)(ws + jb.dstOff);
    #pragma unroll
    for (int rr=0; rr<32; rr+=8)
      dst[(size_t)(tn*32+rr+r)*jb.stride + tk*32 + c] = tile[c][rr+r];
  } else {
    u16* dst = (u16*)(ws + jb.dstOff);
    #pragma unroll
    for (int rr=0; rr<32; rr+=8)
      dst[(size_t)(tn*32+rr+r)*jb.stride + tk*32 + c] = f2bf(tile[c][rr+r]);
  }
}

__global__ void k_embcvt(const float* __restrict__ src, u16* __restrict__ dst, int n4){
  int i = blockIdx.x*blockDim.x + threadIdx.x;
  if (i >= n4) return;
  float4 v = ((const float4*)src)[i];
  uint2 pk;
  pk.x = f2bf(v.x) | ((u32)f2bf(v.y)<<16);
  pk.y = f2bf(v.z) | ((u32)f2bf(v.w)<<16);
  ((uint2*)dst)[i] = pk;
}

// ---------------- fragment packer (64 chunks x [hs:16][lane:64] x 16B per layer) ----------------
__global__ void k_packfrag(const float* __restrict__ srcA, const float* __restrict__ srcB,
                           u16* __restrict__ dst)
{
  int gid = blockIdx.x*256 + threadIdx.x;   // 65536 total
  int lane = gid & 63;
  int hs   = (gid>>6) & 15;
  int c    = gid >> 10;                     // 0..63
  int kc = c>>2, g = c&3;
  int l4 = lane>>4, l15 = lane&15;
  int col = g*256 + hs*16 + l15;
  int k0  = kc*32 + l4*8;
  u16 out[8];
  #pragma unroll
  for (int j=0;j<8;++j){
    int k = k0 + j;
    float v = (k < 256) ? srcA[(size_t)k*1024 + col] : srcB[(size_t)(k-256)*1024 + col];
    out[j] = f2bf(v);
  }
  *(s16x8*)(dst + (size_t)gid*8) = *(const s16x8*)out;
}

// ---------------- persistent fused 2-layer LSTM (LDS weights, one per-sg barrier
// per step, device-scope (LLC) h-exchange) ----------------
__global__ __launch_bounds__(1024,4) void k_lstm3(
    const int* __restrict__ tokens, const u16* __restrict__ EMBB,
    const u16* __restrict__ WP1, const u16* __restrict__ WP2,
    const float* __restrict__ b1, const float* __restrict__ b2,
    u16* __restrict__ H1A, u16* __restrict__ H1B,
    u16* __restrict__ H2A, u16* __restrict__ H2B,
    u32* __restrict__ bar, float* __restrict__ Hall)
{
  __shared__ u16 W1s[64*512];   // 64KB
  __shared__ u16 W2s[64*512];   // 64KB
  const int tid=threadIdx.x, lane=tid&63, v=tid>>6, l15=lane&15, l4=lane>>4;
  const int bid=blockIdx.x, sg=bid&15, hs=bid>>4;
  const int seq0w = sg*512 + v*32;
  u32* slots = bar + sg*16;

  #pragma unroll
  for (int i=0;i<4;++i){
    int c = v*4+i;
    const u16* s1 = WP1 + ((size_t)(c*16+hs))*512 + lane*8;
    const u16* s2 = WP2 + ((size_t)(c*16+hs))*512 + lane*8;
    __builtin_amdgcn_global_load_lds((const __attribute__((address_space(1))) void*)s1,
        (__attribute__((address_space(3))) void*)(W1s + c*512), 16, 0, 0);
    __builtin_amdgcn_global_load_lds((const __attribute__((address_space(1))) void*)s2,
        (__attribute__((address_space(3))) void*)(W2s + c*512), 16, 0, 0);
  }
  float bl1[4], bl2[4];
  #pragma unroll
  for (int g=0;g<4;++g){ bl1[g]=b1[g*256 + hs*16 + l15]; bl2[g]=b2[g*256 + hs*16 + l15]; }
  asm volatile("s_waitcnt vmcnt(0)" ::: "memory");
  __syncthreads();

  float c1[8], c2[8];
  #pragma unroll
  for (int i=0;i<8;++i){ c1[i]=0.f; c2[i]=0.f; }
  const int row0 = seq0w + l15, row1 = seq0w + 16 + l15;
  u32 gen = 0;

  #pragma unroll 1
  for (int t=0;t<32;++t){
    const u16* H1r = (t&1)? H1B : H1A;  u16* H1w = (t&1)? H1A : H1B;
    const u16* H2r = (t&1)? H2B : H2A;  u16* H2w = (t&1)? H2A : H2B;
    const int tok0 = tokens[row0*32 + t], tok1 = tokens[row1*32 + t];
    f32x4 acc[2][4];
    s16x8 r[16];
    // ---- layer 1: z1 = [e_t | h1(t-1)] @ [K1;R1] + b1 ----
    ld16_iss(H1r + (size_t)row0*256 + l4*8, H1r + (size_t)row1*256 + l4*8, r);
    #pragma unroll
    for (int g=0;g<4;++g){ acc[0][g]=splat4(bl1[g]); acc[1][g]=splat4(bl1[g]); }
    #pragma unroll
    for (int kc=0;kc<8;++kc){
      s16x8 fa0 = *(const s16x8*)(EMBB + (size_t)tok0*256 + kc*32 + l4*8);
      s16x8 fa1 = *(const s16x8*)(EMBB + (size_t)tok1*256 + kc*32 + l4*8);
      #pragma unroll
      for (int g=0;g<4;++g){
        s16x8 wf = *(const s16x8*)&W1s[(kc*4+g)*512 + lane*8];
        acc[0][g]=mfma16(fa0,wf,acc[0][g]);
        acc[1][g]=mfma16(fa1,wf,acc[1][g]);
      }
    }
    WAIT0SB();                                  // h1(t-1) operands landed (hidden under EMBB MFMAs)
    #pragma unroll
    for (int k2=0;k2<8;++k2){
      #pragma unroll
      for (int g=0;g<4;++g){
        s16x8 wf = *(const s16x8*)&W1s[((8+k2)*4+g)*512 + lane*8];
        acc[0][g]=mfma16(r[k2],wf,acc[0][g]);
        acc[1][g]=mfma16(r[8+k2],wf,acc[1][g]);
      }
    }
    #pragma unroll
    for (int m=0;m<2;++m)
      #pragma unroll
      for (int rr=0;rr<4;++rr){
        int idx=m*4+rr;
        float zi=acc[m][0][rr], zf=acc[m][1][rr], zg=acc[m][2][rr], zo=acc[m][3][rr];
        float cc=sigm(zf)*c1[idx]+sigm(zi)*tanh_f(zg);
        c1[idx]=cc;
        st16_s(H1w + (size_t)(seq0w + m*16 + l4*4 + rr)*256 + hs*16 + l15,
               f2bf(sigm(zo)*tanh_f(cc)));
      }
    ++gen; sgbar(slots, hs, gen);   // A(t): h1(t) visible; h2(t-1) (stored pre-barrier) visible
    // ---- layer 2: z2 = [h1(t) | h2(t-1)] @ [K2;R2] + b2 ----
    #pragma unroll
    for (int g=0;g<4;++g){ acc[0][g]=splat4(bl2[g]); acc[1][g]=splat4(bl2[g]); }
    ld16_iss(H1w + (size_t)row0*256 + l4*8, H1w + (size_t)row1*256 + l4*8, r);
    WAIT0SB();
    #pragma unroll
    for (int k2=0;k2<8;++k2){
      #pragma unroll
      for (int g=0;g<4;++g){
        s16x8 wf = *(const s16x8*)&W2s[(k2*4+g)*512 + lane*8];
        acc[0][g]=mfma16(r[k2],wf,acc[0][g]);
        acc[1][g]=mfma16(r[8+k2],wf,acc[1][g]);
      }
    }
    ld16_iss(H2r + (size_t)row0*256 + l4*8, H2r + (size_t)row1*256 + l4*8, r);
    WAIT0SB();
    #pragma unroll
    for (int k2=0;k2<8;++k2){
      #pragma unroll
      for (int g=0;g<4;++g){
        s16x8 wf = *(const s16x8*)&W2s[((8+k2)*4+g)*512 + lane*8];
        acc[0][g]=mfma16(r[k2],wf,acc[0][g]);
        acc[1][g]=mfma16(r[8+k2],wf,acc[1][g]);
      }
    }
    #pragma unroll
    for (int m=0;m<2;++m)
      #pragma unroll
      for (int rr=0;rr<4;++rr){
        int idx=m*4+rr;
        float zi=acc[m][0][rr], zf=acc[m][1][rr], zg=acc[m][2][rr], zo=acc[m][3][rr];
        float cc=sigm(zf)*c2[idx]+sigm(zi)*tanh_f(zg);
        c2[idx]=cc;
        float h=sigm(zo)*tanh_f(cc);
        st16_s(H2w + (size_t)(seq0w + m*16 + l4*4 + rr)*256 + hs*16 + l15, f2bf(h));
        if (t==31) Hall[(size_t)(seq0w + m*16 + l4*4 + rr)*256 + hs*16 + l15] = h;
      }
    // no barrier here: h2(t) publishes at A(t+1); kernel end syncs t=31
  }
}

// ---------------- generic bf16 GEMM: C[M][N] = A[M][K] @ Bt[N][K]^T ----------------
// EPI: 0 bf16; 1 +bias,relu,bf16; 4 f32 (guards); 5 +bias,bf16,M-guard;
//      6 +Res, LayerNorm -> X f32 + XB bf16 (N==256, full rows per block)
//      7 +bias +Res, LayerNorm -> X f32 + XB bf16
template<int BM, int EPI>
__global__ __launch_bounds__(512,2) void k_gemm(
    const u16* __restrict__ A, const u16* __restrict__ Bt, void* __restrict__ Cv,
    const float* __restrict__ bias, const float* __restrict__ Res,
    int M, int N, int K, int ldC,
    const float* __restrict__ lng, const float* __restrict__ lnb, u16* __restrict__ outB)
{
  __shared__ u16 Asl[BM*256];
  __shared__ float sS[512];
  __shared__ float sQ[512];
  const int tid=threadIdx.x, lane=tid&63, w=tid>>6, l15=lane&15, l4=lane>>4;
  const int mb=blockIdx.x, nb=blockIdx.y;
  constexpr int MT = BM/16;
  const int col0 = nb*256 + w*32;
  float bz0=0.f, bz1=0.f;
  if (EPI==1 || EPI==5 || EPI==7){ bz0 = bias[col0 + l15]; bz1 = bias[col0 + 16 + l15]; }
  f32x4 acc[MT][2];
  #pragma unroll
  for (int mt=0;mt<MT;++mt){ acc[mt][0]=splat4(bz0); acc[mt][1]=splat4(bz1); }
  for (int kb=0; kb<K; kb+=256){
    __syncthreads();
    if (tid < BM*8){
      int row=tid>>3, part=tid&7;
      int arow = mb*BM+row; if (arow > M-1) arow = M-1;
      const u16* src = A + (size_t)arow*K + kb + part*32;
      #pragma unroll
      for (int i=0;i<4;++i)
        *(s16x8*)&Asl[swz256(row, part*32+i*8)] = *(const s16x8*)(src+i*8);
    }
    __syncthreads();
    #pragma unroll
    for (int kc=0; kc<8; ++kc){
      s16x8 fa[MT];
      #pragma unroll
      for (int mt=0;mt<MT;++mt)
        fa[mt] = *(const s16x8*)&Asl[swz256(mt*16+l15, kc*32 + l4*8)];
      #pragma unroll
      for (int n=0;n<2;++n){
        int brow = col0 + n*16 + l15; if (brow > N-1) brow = N-1;
        const s16x8 fb = *(const s16x8*)(Bt + (size_t)brow*K + kb + kc*32 + l4*8);
        #pragma unroll
        for (int mt=0;mt<MT;++mt) acc[mt][n] = mfma16(fa[mt], fb, acc[mt][n]);
      }
    }
  }
  if constexpr (EPI==6 || EPI==7){
    // fused residual + LayerNorm; block holds full rows (N=256).
    float vv[MT][2][4];
    #pragma unroll
    for (int mt=0;mt<MT;++mt)
      #pragma unroll
      for (int n=0;n<2;++n)
        #pragma unroll
        for (int r=0;r<4;++r){
          int row = mb*BM + mt*16 + l4*4 + r;
          int col = col0 + n*16 + l15;
          vv[mt][n][r] = acc[mt][n][r] + Res[(size_t)row*256 + col];
        }
    #pragma unroll
    for (int mt=0;mt<MT;++mt)
      #pragma unroll
      for (int r=0;r<4;++r){
        float s = vv[mt][0][r] + vv[mt][1][r];
        float q = vv[mt][0][r]*vv[mt][0][r] + vv[mt][1][r]*vv[mt][1][r];
        #pragma unroll
        for (int msk=1;msk<16;msk<<=1){ s += __shfl_xor(s, msk, 64); q += __shfl_xor(q, msk, 64); }
        if (l15==0){ sS[w*64 + mt*16 + l4*4 + r] = s; sQ[w*64 + mt*16 + l4*4 + r] = q; }
      }
    __syncthreads();
    #pragma unroll
    for (int mt=0;mt<MT;++mt)
      #pragma unroll
      for (int r=0;r<4;++r){
        int lrow = mt*16 + l4*4 + r;
        float S=0.f, Q=0.f;
        #pragma unroll
        for (int w2=0;w2<8;++w2){ S += sS[w2*64 + lrow]; Q += sQ[w2*64 + lrow]; }
        float mean = S * (1.f/256.f);
        float var  = Q * (1.f/256.f) - mean*mean;
        float rstd = rsqrtf(var + 1e-5f);
        int row = mb*BM + lrow;
        #pragma unroll
        for (int n=0;n<2;++n){
          int col = col0 + n*16 + l15;
          float ov = (vv[mt][n][r]-mean)*rstd*lng[col] + lnb[col];
          ((float*)Cv)[(size_t)row*256 + col] = ov;
          outB[(size_t)row*256 + col] = f2bf(ov);
        }
      }
  } else {
    #pragma unroll
    for (int mt=0;mt<MT;++mt){
      #pragma unroll
      for (int n=0;n<2;++n){
        #pragma unroll
        for (int r=0;r<4;++r){
          int row = mb*BM + mt*16 + l4*4 + r;
          int col = col0 + n*16 + l15;
          if (col < N && row < M){
            float v = acc[mt][n][r];
            if (EPI==0){ ((u16*)Cv)[(size_t)row*ldC + col] = f2bf(v); }
            else if (EPI==1){ ((u16*)Cv)[(size_t)row*ldC + col] = f2bf(fmaxf(v,0.f)); }
            else if (EPI==5){ ((u16*)Cv)[(size_t)row*ldC + col] = f2bf(v); }
            else { ((float*)Cv)[(size_t)row*ldC + col] = v; }
          }
        }
      }
    }
  }
}

// ---------------- attention, one WG per (b,h) ----------------
__global__ __launch_bounds__(256) void k_attn(const u16* __restrict__ QKV, u16* __restrict__ AO,
                                              const int* __restrict__ pc)
{
  __shared__ u16 Qs[256*32];
  __shared__ u16 Ks[256*32];
  __shared__ u16 Vt[32*256];
  __shared__ u16 Ab[4][64*128];
  const int bh=blockIdx.x, b=bh>>3, h=bh&7;
  const int tid=threadIdx.x, lane=tid&63, w=tid>>6, l15=lane&15, l4=lane>>4;
  const int pcm1 = pc[b]-1;
  {
    int row = tid;
    const u16* base = QKV + (size_t)(b*256+row)*768 + h*32;
    #pragma unroll
    for (int i=0;i<4;++i){
      *(s16x8*)&Qs[swz32(row, i*8)] = *(const s16x8*)(base + i*8);
      *(s16x8*)&Ks[swz32(row, i*8)] = *(const s16x8*)(base + 256 + i*8);
    }
    #pragma unroll
    for (int i=0;i<4;++i){
      s16x8 v = *(const s16x8*)(base + 512 + i*8);
      #pragma unroll
      for (int j=0;j<8;++j){
        int d = i*8+j;
        Vt[d*256 + ((((row>>3) ^ (d&7))&31)<<3) + (row&7)] = (u16)v[j];
      }
    }
  }
  __syncthreads();
  const float scale = 0.17677669529663689f;
  const int q0w = w*64;
  float rmax[4][4], rinv[4][4];
  #pragma unroll 1
  for (int m=0;m<4;++m){
    f32x4 sacc[16];
    #pragma unroll
    for (int nt=0;nt<16;++nt) sacc[nt]=splat4(0.f);
    s16x8 fa = *(const s16x8*)&Qs[swz32(q0w+m*16+l15, l4*8)];
    #pragma unroll
    for (int nt=0;nt<16;++nt){
      s16x8 fb = *(const s16x8*)&Ks[swz32(nt*16+l15, l4*8)];
      sacc[nt] = mfma16(fa, fb, sacc[nt]);
    }
    #pragma unroll
    for (int r=0;r<4;++r){
      int q = q0w + m*16 + l4*4 + r;
      bool vq = q < pcm1;
      float sv[16]; float mx = -3e38f;
      #pragma unroll
      for (int nt=0;nt<16;++nt){
        int k = nt*16 + l15;
        float s = (vq && k < pcm1) ? sacc[nt][r]*scale : -1e9f;
        if (k == 255) s = -1e30f;
        sv[nt] = s; mx = fmaxf(mx, s);
      }
      #pragma unroll
      for (int msk=1;msk<16;msk<<=1) mx = fmaxf(mx, __shfl_xor(mx, msk, 64));
      float sum = 0.f;
      #pragma unroll
      for (int nt=0;nt<16;++nt) sum += __expf(sv[nt]-mx);
      #pragma unroll
      for (int msk=1;msk<16;msk<<=1) sum += __shfl_xor(sum, msk, 64);
      rmax[m][r]=mx; rinv[m][r]=1.f/sum;
    }
  }
  f32x4 oacc[4][2];
  #pragma unroll
  for (int m=0;m<4;++m){ oacc[m][0]=splat4(0.f); oacc[m][1]=splat4(0.f); }
  #pragma unroll 1
  for (int kg=0; kg<2; ++kg){
    #pragma unroll 1
    for (int m=0;m<4;++m){
      s16x8 fa = *(const s16x8*)&Qs[swz32(q0w+m*16+l15, l4*8)];
      #pragma unroll
      for (int nt2=0;nt2<8;++nt2){
        int nt = kg*8 + nt2;
        s16x8 fb = *(const s16x8*)&Ks[swz32(nt*16+l15, l4*8)];
        f32x4 sa = mfma16(fa, fb, splat4(0.f));
        #pragma unroll
        for (int r=0;r<4;++r){
          int q = q0w + m*16 + l4*4 + r;
          int k = nt*16 + l15;
          float s = (q < pcm1 && k < pcm1) ? sa[r]*scale : -1e9f;
          if (k == 255) s = -1e30f;
          float p = __expf(s - rmax[m][r]) * rinv[m][r];
          Ab[w][swz128(m*16 + l4*4 + r, nt2*16 + l15)] = f2bf(p);
        }
      }
    }
    #pragma unroll 1
    for (int m=0;m<4;++m){
      #pragma unroll
      for (int kc=0;kc<4;++kc){
        s16x8 fa2 = *(const s16x8*)&Ab[w][swz128(m*16+l15, kc*32 + l4*8)];
        #pragma unroll
        for (int n=0;n<2;++n){
          int d = n*16 + l15;
          int kch = kg*16 + kc*4 + l4;
          s16x8 fb = *(const s16x8*)&Vt[d*256 + (((kch ^ (d&7))&31)<<3)];
          oacc[m][n] = mfma16(fa2, fb, oacc[m][n]);
        }
      }
    }
  }
  #pragma unroll
  for (int m=0;m<4;++m){
    #pragma unroll
    for (int n=0;n<2;++n){
      #pragma unroll
      for (int r=0;r<4;++r){
        int q = q0w + m*16 + l4*4 + r;
        AO[(size_t)(b*256+q)*256 + h*32 + n*16 + l15] = f2bf(oacc[m][n][r]);
      }
    }
  }
}

// ---------------- build masked encoder input ----------------
__global__ void k_buildZ(const float* __restrict__ Hall, const int* __restrict__ pc,
                         float* __restrict__ X, u16* __restrict__ Xb)
{
  int gid = blockIdx.x*256 + threadIdx.x;   // float4 id, 524288 total
  int row = gid >> 6;
  int b = row >> 8, p = row & 255;
  float4 v; v.x=v.y=v.z=v.w=0.f;
  if (p < pc[b]-1) v = ((const float4*)Hall)[gid];
  ((float4*)X)[gid] = v;
  uint2 pk; pk.x = f2bf(v.x) | ((u32)f2bf(v.y)<<16); pk.y = f2bf(v.z) | ((u32)f2bf(v.w)<<16);
  ((uint2*)Xb)[gid] = pk;
}

// ---------------- R vector: R = relu(C_i[tgt] @ R0) @ W_r ----------------
__global__ void k_rprep(const float* __restrict__ Hall, const int* __restrict__ pc, const int* __restrict__ tgt,
                        const float* __restrict__ CIT, const float* __restrict__ Wr, float* __restrict__ RV)
{
  int b = blockIdx.x, t = threadIdx.x;
  __shared__ float r0[256], ys[256];
  r0[t] = Hall[(size_t)(b*256 + pc[b]-1)*256 + t];
  __syncthreads();
  const float* Cb = CIT + (size_t)tgt[b]*65536;
  float a = 0.f;
  for (int j=0;j<256;++j) a += Cb[j*256 + t] * r0[j];
  ys[t] = fmaxf(a, 0.f);
  __syncthreads();
  float a2 = 0.f;
  for (int i=0;i<256;++i) a2 += Wr[i*256 + t] * ys[i];
  RV[b*256 + t] = a2;
}

// ---------------- pooling ----------------
__global__ void k_pool(const float* __restrict__ X, const float* __restrict__ RV,
                       const float* __restrict__ Wg, u16* __restrict__ HB)
{
  int b = blockIdx.x, t = threadIdx.x;
  __shared__ float R[256], al[256], red[256], zp[256];
  R[t] = RV[b*256+t];
  __syncthreads();
  float sc = -3e38f;
  if (t < 255){
    const float* z = X + (size_t)(b*256+t)*256;
    float a=0.f;
    for (int d=0;d<256;++d) a += z[d]*R[d];
    sc = a;
  }
  red[t] = sc;
  __syncthreads();
  for (int s=128;s>0;s>>=1){ if (t<s) red[t]=fmaxf(red[t],red[t+s]); __syncthreads(); }
  float M = red[0];
  __syncthreads();
  float e = (t<255) ? __expf(sc - M) : 0.f;
  red[t] = e;
  __syncthreads();
  for (int s=128;s>0;s>>=1){ if (t<s) red[t]+=red[t+s]; __syncthreads(); }
  float S = red[0];
  al[t] = e / S;
  __syncthreads();
  float acc = 0.f;
  for (int p=0;p<255;++p) acc += al[p] * X[(size_t)(b*256+p)*256 + t];
  zp[t] = acc;
  __syncthreads();
  float a2 = 0.f;
  for (int d=0;d<256;++d) a2 += zp[d] * Wg[d*256 + t];
  for (int d=0;d<256;++d) a2 += R[d]  * Wg[(256+d)*256 + t];
  HB[b*256+t] = f2bf(fmaxf(a2, 0.f));
}

// ---------------- final vocab softmax ----------------
__global__ void k_osm(const float* __restrict__ LOG, float* __restrict__ out)
{
  int b = blockIdx.x, t = threadIdx.x;  // 512 threads
  __shared__ float red[512];
  const float* Lp = LOG + (size_t)b*30000;
  float mx = -3e38f;
  for (int i=t;i<30000;i+=512) mx = fmaxf(mx, Lp[i]);
  red[t]=mx; __syncthreads();
  for (int s=256;s>0;s>>=1){ if (t<s) red[t]=fmaxf(red[t],red[t+s]); __syncthreads(); }
  float M = red[0]; __syncthreads();
  float sm = 0.f;
  for (int i=t;i<30000;i+=512) sm += __expf(Lp[i]-M);
  red[t]=sm; __syncthreads();
  for (int s=256;s>0;s>>=1){ if (t<s) red[t]+=red[t+s]; __syncthreads(); }
  float rinv = 1.f/red[0];
  float* O = out + (size_t)b*30000;
  for (int i=t;i<30000;i+=512) O[i] = __expf(Lp[i]-M) * rinv;
}

// ---------------- host ----------------
extern "C" void kernel_launch(void* const* d_in, const int* in_sizes, int n_in,
                              void* d_out, int out_size, void* d_ws, size_t ws_size,
                              hipStream_t stream)
{
  const int*   tokens = (const int*)  d_in[0];
  const int*   pc     = (const int*)  d_in[1];
  const int*   tgt    = (const int*)  d_in[2];
  const float* emb    = (const float*)d_in[3];
  const float* l1k    = (const float*)d_in[4];
  const float* l1r    = (const float*)d_in[5];
  const float* l1b    = (const float*)d_in[6];
  const float* l2k    = (const float*)d_in[7];
  const float* l2r    = (const float*)d_in[8];
  const float* l2b    = (const float*)d_in[9];
  const float* wq     = (const float*)d_in[10];
  const float* wk     = (const float*)d_in[11];
  const float* wv     = (const float*)d_in[12];
  const float* wo     = (const float*)d_in[13];
  const float* ln1g   = (const float*)d_in[14];
  const float* ln1b   = (const float*)d_in[15];
  const float* w1e    = (const float*)d_in[16];
  const float* b1e    = (const float*)d_in[17];
  const float* w2e    = (const float*)d_in[18];
  const float* b2e    = (const float*)d_in[19];
  const float* ln2g   = (const float*)d_in[20];
  const float* ln2b   = (const float*)d_in[21];
  const float* Wr     = (const float*)d_in[22];
  const float* Wg     = (const float*)d_in[23];
  const float* Ci     = (const float*)d_in[24];

  char* ws = (char*)d_ws;
  u16*   EMBB = (u16*)  (ws + OFF_EMBB);
  u16*   WP1  = (u16*)  (ws + OFF_WP1);
  u16*   WP2  = (u16*)  (ws + OFF_WP2);
  float* CIT  = (float*)(ws + OFF_CIT);
  float* HALL = (float*)(ws + OFF_HALL);
  float* X    = (float*)(ws + OFF_X);
  u16*   XB   = (u16*)  (ws + OFF_XB);
  u16*   QKVb = (u16*)  (ws + OFF_QKV);
  u16*   AOb  = (u16*)  (ws + OFF_AO);
  u16*   Fb   = (u16*)  (ws + OFF_F);
  float* RV   = (float*)(ws + OFF_RV);
  u16*   HB   = (u16*)  (ws + OFF_HB);
  float* LOGp = (float*)(ws + OFF_LOG);
  u16*   H1A  = (u16*)  (ws + OFF_H1A);
  u16*   H1B  = (u16*)  (ws + OFF_H1B);
  u16*   H2A  = (u16*)  (ws + OFF_H2A);
  u16*   H2B  = (u16*)  (ws + OFF_H2B);
  u32*   BARC = (u32*)  (ws + OFF_BARC);

  PrepArgs pa;
  int ji = 0;
  auto addJ = [&](const float* s, size_t off, int K, int N, int stride, int f32o){
    pa.j[ji].src=s; pa.j[ji].dstOff=(u32)off; pa.j[ji].K=K; pa.j[ji].N=N; pa.j[ji].stride=stride; pa.j[ji].f32out=f32o; ++ji;
  };
  for (int l=0;l<4;++l) addJ(wq + l*65536,  OFF_BQKV + (size_t)(l*768      )*512, 256,256,256,0);
  for (int l=0;l<4;++l) addJ(wk + l*65536,  OFF_BQKV + (size_t)(l*768 + 256)*512, 256,256,256,0);
  for (int l=0;l<4;++l) addJ(wv + l*65536,  OFF_BQKV + (size_t)(l*768 + 512)*512, 256,256,256,0);
  for (int l=0;l<4;++l) addJ(wo + l*65536,  OFF_WOT  + (size_t)l*131072, 256,256,256,0);
  for (int l=0;l<4;++l) addJ(w1e + l*262144, OFF_W1ET + (size_t)l*524288, 256,1024,256,0);
  for (int l=0;l<4;++l) addJ(w2e + l*262144, OFF_W2ET + (size_t)l*524288, 1024,256,1024,0);
  for (int c=0;c<32;++c) addJ(Ci + (size_t)c*65536, OFF_CIT + (size_t)c*262144, 256,256,256,1);

  // zero h(-1) buffers + barrier slot array
  hipMemsetAsync(ws + OFF_H1A, 0, 16777216 + 4096, stream);
  k_prep<<<dim3(256,56), dim3(256), 0, stream>>>(pa, ws);
  k_embcvt<<<dim3(7500), dim3(256), 0, stream>>>(emb, EMBB, 1920000);
  k_packfrag<<<dim3(256), dim3(256), 0, stream>>>(l1k, l1r, WP1);
  k_packfrag<<<dim3(256), dim3(256), 0, stream>>>(l2k, l2r, WP2);
  k_lstm3<<<dim3(256), dim3(1024), 0, stream>>>(tokens, EMBB, WP1, WP2, l1b, l2b,
                                                H1A, H1B, H2A, H2B, BARC, HALL);
  k_buildZ<<<dim3(2048), dim3(256), 0, stream>>>(HALL, pc, X, XB);
  k_rprep<<<dim3(32), dim3(256), 0, stream>>>(HALL, pc, tgt, CIT, Wr, RV);

  u16* BQKV = (u16*)(ws + OFF_BQKV);
  u16* WOT  = (u16*)(ws + OFF_WOT);
  u16* W1ET = (u16*)(ws + OFF_W1ET);
  u16* W2ET = (u16*)(ws + OFF_W2ET);
  for (int l=0;l<4;++l){
    k_gemm<64,0><<<dim3(128,3), dim3(512), 0, stream>>>(XB, BQKV + (size_t)l*768*256, QKVb, nullptr, nullptr, 8192, 768, 256, 768, nullptr, nullptr, nullptr);
    k_attn<<<dim3(256), dim3(256), 0, stream>>>(QKVb, AOb, pc);
    k_gemm<64,6><<<dim3(128,1), dim3(512), 0, stream>>>(AOb, WOT + (size_t)l*65536, X, nullptr, X, 8192, 256, 256, 256, ln1g + l*256, ln1b + l*256, XB);
    k_gemm<64,1><<<dim3(128,4), dim3(512), 0, stream>>>(XB, W1ET + (size_t)l*262144, Fb, b1e + l*1024, nullptr, 8192, 1024, 256, 1024, nullptr, nullptr, nullptr);
    k_gemm<64,7><<<dim3(128,1), dim3(512), 0, stream>>>(Fb, W2ET + (size_t)l*262144, X, b2e + l*256, X, 8192, 256, 1024, 256, ln2g + l*256, ln2b + l*256, XB);
  }

  k_pool<<<dim3(32), dim3(256), 0, stream>>>(X, RV, Wg, HB);
  k_gemm<32,4><<<dim3(1,118), dim3(512), 0, stream>>>(HB, EMBB, LOGp, nullptr, nullptr, 32, 30000, 256, 30000, nullptr, nullptr, nullptr);
  k_osm<<<dim3(32), dim3(512), 0, stream>>>(LOGp, (float*)d_out);
}

// Round 20
// 1940.516 us; speedup vs baseline: 1.2060x; 1.0006x over previous
//
#include <hip/hip_runtime.h>
#include <cstdint>
#include <cstddef>

typedef unsigned short u16;
typedef unsigned int   u32;
typedef float f32x4 __attribute__((ext_vector_type(4)));
typedef short s16x8 __attribute__((ext_vector_type(8)));
typedef u32   u32x4 __attribute__((ext_vector_type(4)));

#define DEV static __device__ __forceinline__
// wait + scheduling fence (rule #18: hipcc hoists reg-only MFMA past inline-asm waits)
#define WAIT0SB() do{ asm volatile("s_waitcnt vmcnt(0)" ::: "memory"); __builtin_amdgcn_sched_barrier(0); }while(0)

// ---------------- problem sizes ----------------
// B=32 P=256 L=32 V=30000 DE=DP=256 NH=8 DH=32 DFF=1024 NL=4, NSEQ=8192

// ---------------- ws layout (bytes) ----------------
static constexpr size_t OFF_EMBB = 0;            // bf16 [30000][256]
static constexpr size_t OFF_WP1  = 15360000;     // bf16 frag-packed [K1;R1] (1MB, 64 chunks x 16KB)
static constexpr size_t OFF_WP2  = 16408576;     // bf16 frag-packed [K2;R2] (1MB)
static constexpr size_t OFF_BQKV = 17457152;     // bf16 [4][768][256]
static constexpr size_t OFF_WOT  = 19030016;     // bf16 [4][256][256]
static constexpr size_t OFF_W1ET = 19554304;     // bf16 [4][1024][256]
static constexpr size_t OFF_W2ET = 21651456;     // bf16 [4][256][1024]
static constexpr size_t OFF_CIT  = 23748608;     // f32  [32][256][256] (C_i^T per mat)
static constexpr size_t OFF_HALL = 32137216;     // f32  [8192][256]
static constexpr size_t OFF_X    = 40525824;     // f32  [8192][256]
static constexpr size_t OFF_XB   = 48914432;     // bf16 [8192][256]
static constexpr size_t OFF_QKV  = 61497344;     // bf16 [8192][768]
static constexpr size_t OFF_AO   = 74080256;     // bf16 [8192][256]
static constexpr size_t OFF_F    = 78274560;     // bf16 [8192][1024]
static constexpr size_t OFF_RV   = 95051776;     // f32  [32][256]
static constexpr size_t OFF_HB   = 95084544;     // bf16 [32][256]
static constexpr size_t OFF_LOG  = 95100928;     // f32  [32][30000]
// LSTM h double-buffers + barrier table live in the dead X..RV region during k_lstm3
static constexpr size_t OFF_H1A  = OFF_X;                 // bf16 [8192][256] = 4MB
static constexpr size_t OFF_H1B  = OFF_X + 4194304;
static constexpr size_t OFF_H2A  = OFF_X + 8388608;
static constexpr size_t OFF_H2B  = OFF_X + 12582912;
static constexpr size_t OFF_BARC = OFF_X + 16777216;      // u32 arr[16][16] (per-sg barrier slots)

// ---------------- helpers ----------------
DEV u16 f2bf(float f){ u32 u = __builtin_bit_cast(u32, f); u += 0x7fffu + ((u>>16)&1u); return (u16)(u>>16); }
DEV float bf2f(u16 v){ return __builtin_bit_cast(float, (u32)v<<16); }
DEV float sigm(float x){ return 1.f/(1.f+__expf(-x)); }
DEV float tanh_f(float x){ float e=__expf(-2.f*fabsf(x)); float t=(1.f-e)/(1.f+e); return x<0.f? -t:t; }
DEV f32x4 splat4(float x){ f32x4 v={x,x,x,x}; return v; }
DEV f32x4 mfma16(s16x8 a, s16x8 b, f32x4 c){ return __builtin_amdgcn_mfma_f32_16x16x32_bf16(a,b,c,0,0,0); }

// XOR swizzles on 16B chunks within a row (row widths 256/128/32 bf16 elems)
DEV int swz256(int row, int col){ int ch=col>>3; return row*256 + (((ch ^ (row&7))&31)<<3) + (col&7); }
DEV int swz128(int row, int col){ int ch=col>>3; return row*128 + (((ch ^ (row&7))&15)<<3) + (col&7); }
DEV int swz32 (int row, int col){ int ch=col>>3; return row*32  + (((ch ^ (row&3))&3)<<3)  + (col&7); }

// ---------------- scope-explicit memory helpers (device scope sc1: cross-XCD coherent,
// LLC-served; validated r18) ----------------
DEV void st32_s(u32* p, u32 v){
  asm volatile("global_store_dword %0, %1, off sc1" :: "v"(p), "v"(v) : "memory");
}
DEV u32 ld32_s(const u32* p){
  u32 r;
  asm volatile("global_load_dword %0, %1, off sc1\n\ts_waitcnt vmcnt(0)" : "=v"(r) : "v"(p) : "memory");
  return r;
}
DEV void st16_s(u16* p, u16 v){
  asm volatile("global_store_short %0, %1, off sc1" :: "v"(p), "v"((u32)v) : "memory");
}
// issue 16 x 16B h-operand loads (two per-lane row addresses, 8 x 64B-offset each), NO wait.
DEV void ld16_iss(const u16* pa, const u16* pb, s16x8 r[16]){
  asm volatile(
    "global_load_dwordx4 %0, %16, off sc1\n\t"
    "global_load_dwordx4 %1, %16, off offset:64 sc1\n\t"
    "global_load_dwordx4 %2, %16, off offset:128 sc1\n\t"
    "global_load_dwordx4 %3, %16, off offset:192 sc1\n\t"
    "global_load_dwordx4 %4, %16, off offset:256 sc1\n\t"
    "global_load_dwordx4 %5, %16, off offset:320 sc1\n\t"
    "global_load_dwordx4 %6, %16, off offset:384 sc1\n\t"
    "global_load_dwordx4 %7, %16, off offset:448 sc1\n\t"
    "global_load_dwordx4 %8, %17, off sc1\n\t"
    "global_load_dwordx4 %9, %17, off offset:64 sc1\n\t"
    "global_load_dwordx4 %10, %17, off offset:128 sc1\n\t"
    "global_load_dwordx4 %11, %17, off offset:192 sc1\n\t"
    "global_load_dwordx4 %12, %17, off offset:256 sc1\n\t"
    "global_load_dwordx4 %13, %17, off offset:320 sc1\n\t"
    "global_load_dwordx4 %14, %17, off offset:384 sc1\n\t"
    "global_load_dwordx4 %15, %17, off offset:448 sc1"
    : "=&v"(r[0]),"=&v"(r[1]),"=&v"(r[2]),"=&v"(r[3]),
      "=&v"(r[4]),"=&v"(r[5]),"=&v"(r[6]),"=&v"(r[7]),
      "=&v"(r[8]),"=&v"(r[9]),"=&v"(r[10]),"=&v"(r[11]),
      "=&v"(r[12]),"=&v"(r[13]),"=&v"(r[14]),"=&v"(r[15])
    : "v"(pa), "v"(pb) : "memory");
}

// ---------------- per-sg 16-WG barrier (device-scope arrivals in LLC) ----------------
DEV void sgbar(u32* slots, int hs, u32 gen){
  __syncthreads();                       // every wave's h-stores drained (vmcnt 0) pre-arrival
  if (threadIdx.x==0){
    asm volatile("s_waitcnt vmcnt(0)" ::: "memory");
    st32_s(slots + hs, gen);
  }
  if (threadIdx.x < 64){
    bool done = false;
    do {
      u32 f = gen;
      if (threadIdx.x < 16) f = ld32_s(slots + threadIdx.x);
      done = __all(f >= gen);
      if (!done) __builtin_amdgcn_s_sleep(2);
    } while(!done);
  }
  __syncthreads();
}

// ---------------- prep: transposes (f32 -> bf16/f32, dst[n][k] = src[k][n]) ----------------
struct TJob { const float* src; u32 dstOff; int K; int N; int stride; int f32out; };
struct PrepArgs { TJob j[60]; };

__global__ void k_prep(PrepArgs pa, char* __restrict__ ws){
  TJob jb = pa.j[blockIdx.y];
  int tilesK = jb.K >> 5, tilesN = jb.N >> 5;
  int ti = blockIdx.x;
  if (ti >= tilesK*tilesN) return;
  int tk = ti % tilesK, tn = ti / tilesK;
  __shared__ float tile[32][33];
  int r = threadIdx.x >> 5, c = threadIdx.x & 31;
  #pragma unroll
  for (int rr=0; rr<32; rr+=8)
    tile[rr+r][c] = jb.src[(size_t)(tk*32+rr+r)*jb.N + tn*32 + c];
  __syncthreads();
  if (jb.f32out){
    float* dst = (float*)(ws + jb.dstOff);
    #pragma unroll
    for (int rr=0; rr<32; rr+=8)
      dst[(size_t)(tn*32+rr+r)*jb.stride + tk*32 + c] = tile[c][rr+r];
  } else {
    u16* dst = (u16*)(ws + jb.dstOff);
    #pragma unroll
    for (int rr=0; rr<32; rr+=8)
      dst[(size_t)(tn*32+rr+r)*jb.stride + tk*32 + c] = f2bf(tile[c][rr+r]);
  }
}

__global__ void k_embcvt(const float* __restrict__ src, u16* __restrict__ dst, int n4){
  int i = blockIdx.x*blockDim.x + threadIdx.x;
  if (i >= n4) return;
  float4 v = ((const float4*)src)[i];
  uint2 pk;
  pk.x = f2bf(v.x) | ((u32)f2bf(v.y)<<16);
  pk.y = f2bf(v.z) | ((u32)f2bf(v.w)<<16);
  ((uint2*)dst)[i] = pk;
}

// ---------------- fragment packer (64 chunks x [hs:16][lane:64] x 16B per layer) ----------------
__global__ void k_packfrag(const float* __restrict__ srcA, const float* __restrict__ srcB,
                           u16* __restrict__ dst)
{
  int gid = blockIdx.x*256 + threadIdx.x;   // 65536 total
  int lane = gid & 63;
  int hs   = (gid>>6) & 15;
  int c    = gid >> 10;                     // 0..63
  int kc = c>>2, g = c&3;
  int l4 = lane>>4, l15 = lane&15;
  int col = g*256 + hs*16 + l15;
  int k0  = kc*32 + l4*8;
  u16 out[8];
  #pragma unroll
  for (int j=0;j<8;++j){
    int k = k0 + j;
    float v = (k < 256) ? srcA[(size_t)k*1024 + col] : srcB[(size_t)(k-256)*1024 + col];
    out[j] = f2bf(v);
  }
  *(s16x8*)(dst + (size_t)gid*8) = *(const s16x8*)out;
}

// ---------------- persistent fused 2-layer LSTM (r18 best-known-good: LDS weights,
// one per-sg device-scope barrier per step, scattered LLC h-stores) ----------------
__global__ __launch_bounds__(1024,4) void k_lstm3(
    const int* __restrict__ tokens, const u16* __restrict__ EMBB,
    const u16* __restrict__ WP1, const u16* __restrict__ WP2,
    const float* __restrict__ b1, const float* __restrict__ b2,
    u16* __restrict__ H1A, u16* __restrict__ H1B,
    u16* __restrict__ H2A, u16* __restrict__ H2B,
    u32* __restrict__ bar, float* __restrict__ Hall)
{
  __shared__ u16 W1s[64*512];   // 64KB
  __shared__ u16 W2s[64*512];   // 64KB
  const int tid=threadIdx.x, lane=tid&63, v=tid>>6, l15=lane&15, l4=lane>>4;
  const int bid=blockIdx.x, sg=bid&15, hs=bid>>4;
  const int seq0w = sg*512 + v*32;
  u32* slots = bar + sg*16;

  #pragma unroll
  for (int i=0;i<4;++i){
    int c = v*4+i;
    const u16* s1 = WP1 + ((size_t)(c*16+hs))*512 + lane*8;
    const u16* s2 = WP2 + ((size_t)(c*16+hs))*512 + lane*8;
    __builtin_amdgcn_global_load_lds((const __attribute__((address_space(1))) void*)s1,
        (__attribute__((address_space(3))) void*)(W1s + c*512), 16, 0, 0);
    __builtin_amdgcn_global_load_lds((const __attribute__((address_space(1))) void*)s2,
        (__attribute__((address_space(3))) void*)(W2s + c*512), 16, 0, 0);
  }
  float bl1[4], bl2[4];
  #pragma unroll
  for (int g=0;g<4;++g){ bl1[g]=b1[g*256 + hs*16 + l15]; bl2[g]=b2[g*256 + hs*16 + l15]; }
  asm volatile("s_waitcnt vmcnt(0)" ::: "memory");
  __syncthreads();

  float c1[8], c2[8];
  #pragma unroll
  for (int i=0;i<8;++i){ c1[i]=0.f; c2[i]=0.f; }
  const int row0 = seq0w + l15, row1 = seq0w + 16 + l15;
  u32 gen = 0;

  #pragma unroll 1
  for (int t=0;t<32;++t){
    const u16* H1r = (t&1)? H1B : H1A;  u16* H1w = (t&1)? H1A : H1B;
    const u16* H2r = (t&1)? H2B : H2A;  u16* H2w = (t&1)? H2A : H2B;
    const int tok0 = tokens[row0*32 + t], tok1 = tokens[row1*32 + t];
    f32x4 acc[2][4];
    s16x8 r[16];
    // ---- layer 1: z1 = [e_t | h1(t-1)] @ [K1;R1] + b1 ----
    ld16_iss(H1r + (size_t)row0*256 + l4*8, H1r + (size_t)row1*256 + l4*8, r);
    #pragma unroll
    for (int g=0;g<4;++g){ acc[0][g]=splat4(bl1[g]); acc[1][g]=splat4(bl1[g]); }
    #pragma unroll
    for (int kc=0;kc<8;++kc){
      s16x8 fa0 = *(const s16x8*)(EMBB + (size_t)tok0*256 + kc*32 + l4*8);
      s16x8 fa1 = *(const s16x8*)(EMBB + (size_t)tok1*256 + kc*32 + l4*8);
      #pragma unroll
      for (int g=0;g<4;++g){
        s16x8 wf = *(const s16x8*)&W1s[(kc*4+g)*512 + lane*8];
        acc[0][g]=mfma16(fa0,wf,acc[0][g]);
        acc[1][g]=mfma16(fa1,wf,acc[1][g]);
      }
    }
    WAIT0SB();                                  // h1(t-1) operands landed (hidden under EMBB MFMAs)
    #pragma unroll
    for (int k2=0;k2<8;++k2){
      #pragma unroll
      for (int g=0;g<4;++g){
        s16x8 wf = *(const s16x8*)&W1s[((8+k2)*4+g)*512 + lane*8];
        acc[0][g]=mfma16(r[k2],wf,acc[0][g]);
        acc[1][g]=mfma16(r[8+k2],wf,acc[1][g]);
      }
    }
    #pragma unroll
    for (int m=0;m<2;++m)
      #pragma unroll
      for (int rr=0;rr<4;++rr){
        int idx=m*4+rr;
        float zi=acc[m][0][rr], zf=acc[m][1][rr], zg=acc[m][2][rr], zo=acc[m][3][rr];
        float cc=sigm(zf)*c1[idx]+sigm(zi)*tanh_f(zg);
        c1[idx]=cc;
        st16_s(H1w + (size_t)(seq0w + m*16 + l4*4 + rr)*256 + hs*16 + l15,
               f2bf(sigm(zo)*tanh_f(cc)));
      }
    ++gen; sgbar(slots, hs, gen);   // A(t): h1(t) visible; h2(t-1) (stored pre-barrier) visible
    // ---- layer 2: z2 = [h1(t) | h2(t-1)] @ [K2;R2] + b2 ----
    #pragma unroll
    for (int g=0;g<4;++g){ acc[0][g]=splat4(bl2[g]); acc[1][g]=splat4(bl2[g]); }
    ld16_iss(H1w + (size_t)row0*256 + l4*8, H1w + (size_t)row1*256 + l4*8, r);
    WAIT0SB();
    #pragma unroll
    for (int k2=0;k2<8;++k2){
      #pragma unroll
      for (int g=0;g<4;++g){
        s16x8 wf = *(const s16x8*)&W2s[(k2*4+g)*512 + lane*8];
        acc[0][g]=mfma16(r[k2],wf,acc[0][g]);
        acc[1][g]=mfma16(r[8+k2],wf,acc[1][g]);
      }
    }
    ld16_iss(H2r + (size_t)row0*256 + l4*8, H2r + (size_t)row1*256 + l4*8, r);
    WAIT0SB();
    #pragma unroll
    for (int k2=0;k2<8;++k2){
      #pragma unroll
      for (int g=0;g<4;++g){
        s16x8 wf = *(const s16x8*)&W2s[((8+k2)*4+g)*512 + lane*8];
        acc[0][g]=mfma16(r[k2],wf,acc[0][g]);
        acc[1][g]=mfma16(r[8+k2],wf,acc[1][g]);
      }
    }
    #pragma unroll
    for (int m=0;m<2;++m)
      #pragma unroll
      for (int rr=0;rr<4;++rr){
        int idx=m*4+rr;
        float zi=acc[m][0][rr], zf=acc[m][1][rr], zg=acc[m][2][rr], zo=acc[m][3][rr];
        float cc=sigm(zf)*c2[idx]+sigm(zi)*tanh_f(zg);
        c2[idx]=cc;
        float h=sigm(zo)*tanh_f(cc);
        st16_s(H2w + (size_t)(seq0w + m*16 + l4*4 + rr)*256 + hs*16 + l15, f2bf(h));
        if (t==31) Hall[(size_t)(seq0w + m*16 + l4*4 + rr)*256 + hs*16 + l15] = h;
      }
    // no barrier here: h2(t) publishes at A(t+1); kernel end syncs t=31
  }
}

// ---------------- generic bf16 GEMM: C[M][N] = A[M][K] @ Bt[N][K]^T ----------------
// EPI: 0 bf16; 1 +bias,relu,bf16; 4 f32 (guards); 5 +bias,bf16,M-guard;
//      6 +Res, LayerNorm -> X f32 + XB bf16 (N==256, full rows per block)
//      7 +bias +Res, LayerNorm -> X f32 + XB bf16
template<int BM, int EPI>
__global__ __launch_bounds__(512,2) void k_gemm(
    const u16* __restrict__ A, const u16* __restrict__ Bt, void* __restrict__ Cv,
    const float* __restrict__ bias, const float* __restrict__ Res,
    int M, int N, int K, int ldC,
    const float* __restrict__ lng, const float* __restrict__ lnb, u16* __restrict__ outB)
{
  __shared__ u16 Asl[BM*256];
  __shared__ float sS[512];
  __shared__ float sQ[512];
  const int tid=threadIdx.x, lane=tid&63, w=tid>>6, l15=lane&15, l4=lane>>4;
  const int mb=blockIdx.x, nb=blockIdx.y;
  constexpr int MT = BM/16;
  const int col0 = nb*256 + w*32;
  float bz0=0.f, bz1=0.f;
  if (EPI==1 || EPI==5 || EPI==7){ bz0 = bias[col0 + l15]; bz1 = bias[col0 + 16 + l15]; }
  f32x4 acc[MT][2];
  #pragma unroll
  for (int mt=0;mt<MT;++mt){ acc[mt][0]=splat4(bz0); acc[mt][1]=splat4(bz1); }
  for (int kb=0; kb<K; kb+=256){
    __syncthreads();
    if (tid < BM*8){
      int row=tid>>3, part=tid&7;
      int arow = mb*BM+row; if (arow > M-1) arow = M-1;
      const u16* src = A + (size_t)arow*K + kb + part*32;
      #pragma unroll
      for (int i=0;i<4;++i)
        *(s16x8*)&Asl[swz256(row, part*32+i*8)] = *(const s16x8*)(src+i*8);
    }
    __syncthreads();
    #pragma unroll
    for (int kc=0; kc<8; ++kc){
      s16x8 fa[MT];
      #pragma unroll
      for (int mt=0;mt<MT;++mt)
        fa[mt] = *(const s16x8*)&Asl[swz256(mt*16+l15, kc*32 + l4*8)];
      #pragma unroll
      for (int n=0;n<2;++n){
        int brow = col0 + n*16 + l15; if (brow > N-1) brow = N-1;
        const s16x8 fb = *(const s16x8*)(Bt + (size_t)brow*K + kb + kc*32 + l4*8);
        #pragma unroll
        for (int mt=0;mt<MT;++mt) acc[mt][n] = mfma16(fa[mt], fb, acc[mt][n]);
      }
    }
  }
  if constexpr (EPI==6 || EPI==7){
    // fused residual + LayerNorm; block holds full rows (N=256).
    float vv[MT][2][4];
    #pragma unroll
    for (int mt=0;mt<MT;++mt)
      #pragma unroll
      for (int n=0;n<2;++n)
        #pragma unroll
        for (int r=0;r<4;++r){
          int row = mb*BM + mt*16 + l4*4 + r;
          int col = col0 + n*16 + l15;
          vv[mt][n][r] = acc[mt][n][r] + Res[(size_t)row*256 + col];
        }
    #pragma unroll
    for (int mt=0;mt<MT;++mt)
      #pragma unroll
      for (int r=0;r<4;++r){
        float s = vv[mt][0][r] + vv[mt][1][r];
        float q = vv[mt][0][r]*vv[mt][0][r] + vv[mt][1][r]*vv[mt][1][r];
        #pragma unroll
        for (int msk=1;msk<16;msk<<=1){ s += __shfl_xor(s, msk, 64); q += __shfl_xor(q, msk, 64); }
        if (l15==0){ sS[w*64 + mt*16 + l4*4 + r] = s; sQ[w*64 + mt*16 + l4*4 + r] = q; }
      }
    __syncthreads();
    #pragma unroll
    for (int mt=0;mt<MT;++mt)
      #pragma unroll
      for (int r=0;r<4;++r){
        int lrow = mt*16 + l4*4 + r;
        float S=0.f, Q=0.f;
        #pragma unroll
        for (int w2=0;w2<8;++w2){ S += sS[w2*64 + lrow]; Q += sQ[w2*64 + lrow]; }
        float mean = S * (1.f/256.f);
        float var  = Q * (1.f/256.f) - mean*mean;
        float rstd = rsqrtf(var + 1e-5f);
        int row = mb*BM + lrow;
        #pragma unroll
        for (int n=0;n<2;++n){
          int col = col0 + n*16 + l15;
          float ov = (vv[mt][n][r]-mean)*rstd*lng[col] + lnb[col];
          ((float*)Cv)[(size_t)row*256 + col] = ov;
          outB[(size_t)row*256 + col] = f2bf(ov);
        }
      }
  } else {
    #pragma unroll
    for (int mt=0;mt<MT;++mt){
      #pragma unroll
      for (int n=0;n<2;++n){
        #pragma unroll
        for (int r=0;r<4;++r){
          int row = mb*BM + mt*16 + l4*4 + r;
          int col = col0 + n*16 + l15;
          if (col < N && row < M){
            float v = acc[mt][n][r];
            if (EPI==0){ ((u16*)Cv)[(size_t)row*ldC + col] = f2bf(v); }
            else if (EPI==1){ ((u16*)Cv)[(size_t)row*ldC + col] = f2bf(fmaxf(v,0.f)); }
            else if (EPI==5){ ((u16*)Cv)[(size_t)row*ldC + col] = f2bf(v); }
            else { ((float*)Cv)[(size_t)row*ldC + col] = v; }
          }
        }
      }
    }
  }
}

// ---------------- attention, one WG per (b,h) ----------------
__global__ __launch_bounds__(256) void k_attn(const u16* __restrict__ QKV, u16* __restrict__ AO,
                                              const int* __restrict__ pc)
{
  __shared__ u16 Qs[256*32];
  __shared__ u16 Ks[256*32];
  __shared__ u16 Vt[32*256];
  __shared__ u16 Ab[4][64*128];
  const int bh=blockIdx.x, b=bh>>3, h=bh&7;
  const int tid=threadIdx.x, lane=tid&63, w=tid>>6, l15=lane&15, l4=lane>>4;
  const int pcm1 = pc[b]-1;
  {
    int row = tid;
    const u16* base = QKV + (size_t)(b*256+row)*768 + h*32;
    #pragma unroll
    for (int i=0;i<4;++i){
      *(s16x8*)&Qs[swz32(row, i*8)] = *(const s16x8*)(base + i*8);
      *(s16x8*)&Ks[swz32(row, i*8)] = *(const s16x8*)(base + 256 + i*8);
    }
    #pragma unroll
    for (int i=0;i<4;++i){
      s16x8 v = *(const s16x8*)(base + 512 + i*8);
      #pragma unroll
      for (int j=0;j<8;++j){
        int d = i*8+j;
        Vt[d*256 + ((((row>>3) ^ (d&7))&31)<<3) + (row&7)] = (u16)v[j];
      }
    }
  }
  __syncthreads();
  const float scale = 0.17677669529663689f;
  const int q0w = w*64;
  float rmax[4][4], rinv[4][4];
  #pragma unroll 1
  for (int m=0;m<4;++m){
    f32x4 sacc[16];
    #pragma unroll
    for (int nt=0;nt<16;++nt) sacc[nt]=splat4(0.f);
    s16x8 fa = *(const s16x8*)&Qs[swz32(q0w+m*16+l15, l4*8)];
    #pragma unroll
    for (int nt=0;nt<16;++nt){
      s16x8 fb = *(const s16x8*)&Ks[swz32(nt*16+l15, l4*8)];
      sacc[nt] = mfma16(fa, fb, sacc[nt]);
    }
    #pragma unroll
    for (int r=0;r<4;++r){
      int q = q0w + m*16 + l4*4 + r;
      bool vq = q < pcm1;
      float sv[16]; float mx = -3e38f;
      #pragma unroll
      for (int nt=0;nt<16;++nt){
        int k = nt*16 + l15;
        float s = (vq && k < pcm1) ? sacc[nt][r]*scale : -1e9f;
        if (k == 255) s = -1e30f;
        sv[nt] = s; mx = fmaxf(mx, s);
      }
      #pragma unroll
      for (int msk=1;msk<16;msk<<=1) mx = fmaxf(mx, __shfl_xor(mx, msk, 64));
      float sum = 0.f;
      #pragma unroll
      for (int nt=0;nt<16;++nt) sum += __expf(sv[nt]-mx);
      #pragma unroll
      for (int msk=1;msk<16;msk<<=1) sum += __shfl_xor(sum, msk, 64);
      rmax[m][r]=mx; rinv[m][r]=1.f/sum;
    }
  }
  f32x4 oacc[4][2];
  #pragma unroll
  for (int m=0;m<4;++m){ oacc[m][0]=splat4(0.f); oacc[m][1]=splat4(0.f); }
  #pragma unroll 1
  for (int kg=0; kg<2; ++kg){
    #pragma unroll 1
    for (int m=0;m<4;++m){
      s16x8 fa = *(const s16x8*)&Qs[swz32(q0w+m*16+l15, l4*8)];
      #pragma unroll
      for (int nt2=0;nt2<8;++nt2){
        int nt = kg*8 + nt2;
        s16x8 fb = *(const s16x8*)&Ks[swz32(nt*16+l15, l4*8)];
        f32x4 sa = mfma16(fa, fb, splat4(0.f));
        #pragma unroll
        for (int r=0;r<4;++r){
          int q = q0w + m*16 + l4*4 + r;
          int k = nt*16 + l15;
          float s = (q < pcm1 && k < pcm1) ? sa[r]*scale : -1e9f;
          if (k == 255) s = -1e30f;
          float p = __expf(s - rmax[m][r]) * rinv[m][r];
          Ab[w][swz128(m*16 + l4*4 + r, nt2*16 + l15)] = f2bf(p);
        }
      }
    }
    #pragma unroll 1
    for (int m=0;m<4;++m){
      #pragma unroll
      for (int kc=0;kc<4;++kc){
        s16x8 fa2 = *(const s16x8*)&Ab[w][swz128(m*16+l15, kc*32 + l4*8)];
        #pragma unroll
        for (int n=0;n<2;++n){
          int d = n*16 + l15;
          int kch = kg*16 + kc*4 + l4;
          s16x8 fb = *(const s16x8*)&Vt[d*256 + (((kch ^ (d&7))&31)<<3)];
          oacc[m][n] = mfma16(fa2, fb, oacc[m][n]);
        }
      }
    }
  }
  #pragma unroll
  for (int m=0;m<4;++m){
    #pragma unroll
    for (int n=0;n<2;++n){
      #pragma unroll
      for (int r=0;r<4;++r){
        int q = q0w + m*16 + l4*4 + r;
        AO[(size_t)(b*256+q)*256 + h*32 + n*16 + l15] = f2bf(oacc[m][n][r]);
      }
    }
  }
}

// ---------------- build masked encoder input ----------------
__global__ void k_buildZ(const float* __restrict__ Hall, const int* __restrict__ pc,
                         float* __restrict__ X, u16* __restrict__ Xb)
{
  int gid = blockIdx.x*256 + threadIdx.x;   // float4 id, 524288 total
  int row = gid >> 6;
  int b = row >> 8, p = row & 255;
  float4 v; v.x=v.y=v.z=v.w=0.f;
  if (p < pc[b]-1) v = ((const float4*)Hall)[gid];
  ((float4*)X)[gid] = v;
  uint2 pk; pk.x = f2bf(v.x) | ((u32)f2bf(v.y)<<16); pk.y = f2bf(v.z) | ((u32)f2bf(v.w)<<16);
  ((uint2*)Xb)[gid] = pk;
}

// ---------------- R vector: R = relu(C_i[tgt] @ R0) @ W_r ----------------
__global__ void k_rprep(const float* __restrict__ Hall, const int* __restrict__ pc, const int* __restrict__ tgt,
                        const float* __restrict__ CIT, const float* __restrict__ Wr, float* __restrict__ RV)
{
  int b = blockIdx.x, t = threadIdx.x;
  __shared__ float r0[256], ys[256];
  r0[t] = Hall[(size_t)(b*256 + pc[b]-1)*256 + t];
  __syncthreads();
  const float* Cb = CIT + (size_t)tgt[b]*65536;
  float a = 0.f;
  for (int j=0;j<256;++j) a += Cb[j*256 + t] * r0[j];
  ys[t] = fmaxf(a, 0.f);
  __syncthreads();
  float a2 = 0.f;
  for (int i=0;i<256;++i) a2 += Wr[i*256 + t] * ys[i];
  RV[b*256 + t] = a2;
}

// ---------------- pooling ----------------
__global__ void k_pool(const float* __restrict__ X, const float* __restrict__ RV,
                       const float* __restrict__ Wg, u16* __restrict__ HB)
{
  int b = blockIdx.x, t = threadIdx.x;
  __shared__ float R[256], al[256], red[256], zp[256];
  R[t] = RV[b*256+t];
  __syncthreads();
  float sc = -3e38f;
  if (t < 255){
    const float* z = X + (size_t)(b*256+t)*256;
    float a=0.f;
    for (int d=0;d<256;++d) a += z[d]*R[d];
    sc = a;
  }
  red[t] = sc;
  __syncthreads();
  for (int s=128;s>0;s>>=1){ if (t<s) red[t]=fmaxf(red[t],red[t+s]); __syncthreads(); }
  float M = red[0];
  __syncthreads();
  float e = (t<255) ? __expf(sc - M) : 0.f;
  red[t] = e;
  __syncthreads();
  for (int s=128;s>0;s>>=1){ if (t<s) red[t]+=red[t+s]; __syncthreads(); }
  float S = red[0];
  al[t] = e / S;
  __syncthreads();
  float acc = 0.f;
  for (int p=0;p<255;++p) acc += al[p] * X[(size_t)(b*256+p)*256 + t];
  zp[t] = acc;
  __syncthreads();
  float a2 = 0.f;
  for (int d=0;d<256;++d) a2 += zp[d] * Wg[d*256 + t];
  for (int d=0;d<256;++d) a2 += R[d]  * Wg[(256+d)*256 + t];
  HB[b*256+t] = f2bf(fmaxf(a2, 0.f));
}

// ---------------- final vocab softmax ----------------
__global__ void k_osm(const float* __restrict__ LOG, float* __restrict__ out)
{
  int b = blockIdx.x, t = threadIdx.x;  // 512 threads
  __shared__ float red[512];
  const float* Lp = LOG + (size_t)b*30000;
  float mx = -3e38f;
  for (int i=t;i<30000;i+=512) mx = fmaxf(mx, Lp[i]);
  red[t]=mx; __syncthreads();
  for (int s=256;s>0;s>>=1){ if (t<s) red[t]=fmaxf(red[t],red[t+s]); __syncthreads(); }
  float M = red[0]; __syncthreads();
  float sm = 0.f;
  for (int i=t;i<30000;i+=512) sm += __expf(Lp[i]-M);
  red[t]=sm; __syncthreads();
  for (int s=256;s>0;s>>=1){ if (t<s) red[t]+=red[t+s]; __syncthreads(); }
  float rinv = 1.f/red[0];
  float* O = out + (size_t)b*30000;
  for (int i=t;i<30000;i+=512) O[i] = __expf(Lp[i]-M) * rinv;
}

// ---------------- host ----------------
extern "C" void kernel_launch(void* const* d_in, const int* in_sizes, int n_in,
                              void* d_out, int out_size, void* d_ws, size_t ws_size,
                              hipStream_t stream)
{
  const int*   tokens = (const int*)  d_in[0];
  const int*   pc     = (const int*)  d_in[1];
  const int*   tgt    = (const int*)  d_in[2];
  const float* emb    = (const float*)d_in[3];
  const float* l1k    = (const float*)d_in[4];
  const float* l1r    = (const float*)d_in[5];
  const float* l1b    = (const float*)d_in[6];
  const float* l2k    = (const float*)d_in[7];
  const float* l2r    = (const float*)d_in[8];
  const float* l2b    = (const float*)d_in[9];
  const float* wq     = (const float*)d_in[10];
  const float* wk     = (const float*)d_in[11];
  const float* wv     = (const float*)d_in[12];
  const float* wo     = (const float*)d_in[13];
  const float* ln1g   = (const float*)d_in[14];
  const float* ln1b   = (const float*)d_in[15];
  const float* w1e    = (const float*)d_in[16];
  const float* b1e    = (const float*)d_in[17];
  const float* w2e    = (const float*)d_in[18];
  const float* b2e    = (const float*)d_in[19];
  const float* ln2g   = (const float*)d_in[20];
  const float* ln2b   = (const float*)d_in[21];
  const float* Wr     = (const float*)d_in[22];
  const float* Wg     = (const float*)d_in[23];
  const float* Ci     = (const float*)d_in[24];

  char* ws = (char*)d_ws;
  u16*   EMBB = (u16*)  (ws + OFF_EMBB);
  u16*   WP1  = (u16*)  (ws + OFF_WP1);
  u16*   WP2  = (u16*)  (ws + OFF_WP2);
  float* CIT  = (float*)(ws + OFF_CIT);
  float* HALL = (float*)(ws + OFF_HALL);
  float* X    = (float*)(ws + OFF_X);
  u16*   XB   = (u16*)  (ws + OFF_XB);
  u16*   QKVb = (u16*)  (ws + OFF_QKV);
  u16*   AOb  = (u16*)  (ws + OFF_AO);
  u16*   Fb   = (u16*)  (ws + OFF_F);
  float* RV   = (float*)(ws + OFF_RV);
  u16*   HB   = (u16*)  (ws + OFF_HB);
  float* LOGp = (float*)(ws + OFF_LOG);
  u16*   H1A  = (u16*)  (ws + OFF_H1A);
  u16*   H1B  = (u16*)  (ws + OFF_H1B);
  u16*   H2A  = (u16*)  (ws + OFF_H2A);
  u16*   H2B  = (u16*)  (ws + OFF_H2B);
  u32*   BARC = (u32*)  (ws + OFF_BARC);

  PrepArgs pa;
  int ji = 0;
  auto addJ = [&](const float* s, size_t off, int K, int N, int stride, int f32o){
    pa.j[ji].src=s; pa.j[ji].dstOff=(u32)off; pa.j[ji].K=K; pa.j[ji].N=N; pa.j[ji].stride=stride; pa.j[ji].f32out=f32o; ++ji;
  };
  for (int l=0;l<4;++l) addJ(wq + l*65536,  OFF_BQKV + (size_t)(l*768      )*512, 256,256,256,0);
  for (int l=0;l<4;++l) addJ(wk + l*65536,  OFF_BQKV + (size_t)(l*768 + 256)*512, 256,256,256,0);
  for (int l=0;l<4;++l) addJ(wv + l*65536,  OFF_BQKV + (size_t)(l*768 + 512)*512, 256,256,256,0);
  for (int l=0;l<4;++l) addJ(wo + l*65536,  OFF_WOT  + (size_t)l*131072, 256,256,256,0);
  for (int l=0;l<4;++l) addJ(w1e + l*262144, OFF_W1ET + (size_t)l*524288, 256,1024,256,0);
  for (int l=0;l<4;++l) addJ(w2e + l*262144, OFF_W2ET + (size_t)l*524288, 1024,256,1024,0);
  for (int c=0;c<32;++c) addJ(Ci + (size_t)c*65536, OFF_CIT + (size_t)c*262144, 256,256,256,1);

  // zero h(-1) buffers + barrier slot array
  hipMemsetAsync(ws + OFF_H1A, 0, 16777216 + 4096, stream);
  k_prep<<<dim3(256,56), dim3(256), 0, stream>>>(pa, ws);
  k_embcvt<<<dim3(7500), dim3(256), 0, stream>>>(emb, EMBB, 1920000);
  k_packfrag<<<dim3(256), dim3(256), 0, stream>>>(l1k, l1r, WP1);
  k_packfrag<<<dim3(256), dim3(256), 0, stream>>>(l2k, l2r, WP2);
  k_lstm3<<<dim3(256), dim3(1024), 0, stream>>>(tokens, EMBB, WP1, WP2, l1b, l2b,
                                                H1A, H1B, H2A, H2B, BARC, HALL);
  k_buildZ<<<dim3(2048), dim3(256), 0, stream>>>(HALL, pc, X, XB);
  k_rprep<<<dim3(32), dim3(256), 0, stream>>>(HALL, pc, tgt, CIT, Wr, RV);

  u16* BQKV = (u16*)(ws + OFF_BQKV);
  u16* WOT  = (u16*)(ws + OFF_WOT);
  u16* W1ET = (u16*)(ws + OFF_W1ET);
  u16* W2ET = (u16*)(ws + OFF_W2ET);
  for (int l=0;l<4;++l){
    k_gemm<64,0><<<dim3(128,3), dim3(512), 0, stream>>>(XB, BQKV + (size_t)l*768*256, QKVb, nullptr, nullptr, 8192, 768, 256, 768, nullptr, nullptr, nullptr);
    k_attn<<<dim3(256), dim3(256), 0, stream>>>(QKVb, AOb, pc);
    k_gemm<64,6><<<dim3(128,1), dim3(512), 0, stream>>>(AOb, WOT + (size_t)l*65536, X, nullptr, X, 8192, 256, 256, 256, ln1g + l*256, ln1b + l*256, XB);
    k_gemm<64,1><<<dim3(128,4), dim3(512), 0, stream>>>(XB, W1ET + (size_t)l*262144, Fb, b1e + l*1024, nullptr, 8192, 1024, 256, 1024, nullptr, nullptr, nullptr);
    k_gemm<64,7><<<dim3(128,1), dim3(512), 0, stream>>>(Fb, W2ET + (size_t)l*262144, X, b2e + l*256, X, 8192, 256, 1024, 256, ln2g + l*256, ln2b + l*256, XB);
  }

  k_pool<<<dim3(32), dim3(256), 0, stream>>>(X, RV, Wg, HB);
  k_gemm<32,4><<<dim3(1,118), dim3(512), 0, stream>>>(HB, EMBB, LOGp, nullptr, nullptr, 32, 30000, 256, 30000, nullptr, nullptr, nullptr);
  k_osm<<<dim3(32), dim3(512), 0, stream>>>(LOGp, (float*)d_out);
}